// Round 1
// baseline (597.092 us; speedup 1.0000x reference)
//
#include <hip/hip_runtime.h>
#include <hip/hip_bf16.h>
#include <math.h>

#define T_TOK 4096
#define D_MODEL 1024
#define L_LAT 256
#define H_HID 512
#define E_EXP 8
#define SH_HID 512

#define BM 64
#define BN 64
#define BK 16

// ---------------- router: logits, top-2, softmax, expert counts ----------------
__global__ void zero_counts_kernel(int* counts) {
    if (threadIdx.x < E_EXP) counts[threadIdx.x] = 0;
}

__global__ void router_kernel(const float* __restrict__ x,
                              const float* __restrict__ w_router,
                              int* __restrict__ topk_idx,
                              float* __restrict__ topk_w,
                              int* __restrict__ counts)
{
    int wid = threadIdx.x >> 6;
    int lane = threadIdx.x & 63;
    int t = blockIdx.x * 4 + wid;
    if (t >= T_TOK) return;
    const float* xr = x + (size_t)t * D_MODEL;

    float acc[E_EXP];
#pragma unroll
    for (int e = 0; e < E_EXP; ++e) acc[e] = 0.f;

    for (int i = 0; i < D_MODEL / 64; ++i) {
        int d = lane + i * 64;
        float xv = xr[d];
#pragma unroll
        for (int e = 0; e < E_EXP; ++e)
            acc[e] = fmaf(xv, w_router[e * D_MODEL + d], acc[e]);
    }
#pragma unroll
    for (int e = 0; e < E_EXP; ++e) {
        for (int off = 32; off > 0; off >>= 1)
            acc[e] += __shfl_xor(acc[e], off, 64);
    }
    if (lane == 0) {
        // top-2, ties -> lower index first (matches jax.lax.top_k)
        int i0 = 0; float v0 = acc[0];
#pragma unroll
        for (int e = 1; e < E_EXP; ++e) if (acc[e] > v0) { v0 = acc[e]; i0 = e; }
        int i1 = -1; float v1 = -INFINITY;
#pragma unroll
        for (int e = 0; e < E_EXP; ++e) if (e != i0 && acc[e] > v1) { v1 = acc[e]; i1 = e; }
        float e1 = expf(v1 - v0);
        float w0 = 1.f / (1.f + e1);
        float w1 = e1 / (1.f + e1);
        topk_idx[2 * t] = i0; topk_idx[2 * t + 1] = i1;
        topk_w[2 * t] = w0;  topk_w[2 * t + 1] = w1;
        atomicAdd(&counts[i0], 1);
        atomicAdd(&counts[i1], 1);
    }
}

__global__ void prep_kernel(const int* __restrict__ counts,
                            int* __restrict__ offsets,
                            int* __restrict__ cursor)
{
    if (threadIdx.x == 0) {
        int acc = 0;
        for (int e = 0; e < E_EXP; ++e) { offsets[e] = acc; cursor[e] = acc; acc += counts[e]; }
    }
}

__global__ void scatter_kernel(const int* __restrict__ topk_idx,
                               int* __restrict__ cursor,
                               int* __restrict__ tok_of_row,
                               int* __restrict__ row_of_pair)
{
    int t = blockIdx.x * blockDim.x + threadIdx.x;
    if (t >= T_TOK) return;
#pragma unroll
    for (int s = 0; s < 2; ++s) {
        int e = topk_idx[2 * t + s];
        int p = atomicAdd(&cursor[e], 1);
        tok_of_row[p] = t;
        row_of_pair[2 * t + s] = p;
    }
}

// ---------------- generic NT GEMM (A: MxK rowmajor, B: NxK rowmajor, C: MxN) ----------
// DUAL: two B matrices -> two accumulators; SILU: C = silu(acc0)*acc1;
// ACC: C += v; EXPERT: per-expert bucketed rows (blockIdx.z = expert);
// GATHER: A row index via tok_of_row[].
template<bool DUAL, bool SILU, bool ACC, bool EXPERT, bool GATHER>
__global__ __launch_bounds__(256)
void gemm_nt(const float* __restrict__ A,
             const float* __restrict__ B0g,
             const float* __restrict__ B1g,
             float* __restrict__ C,
             int M, int N, int K,
             const int* __restrict__ tok_of_row,
             const int* __restrict__ offsets,
             const int* __restrict__ counts,
             long strideB)
{
    __shared__ float As[BK][BM + 4];
    __shared__ float Bs0[BK][BN + 4];
    __shared__ float Bs1[DUAL ? BK : 1][DUAL ? (BN + 4) : 1];

    int e = EXPERT ? blockIdx.z : 0;
    int m_base = 0, m_count = M;
    if (EXPERT) { m_base = offsets[e]; m_count = counts[e]; }
    int m0 = blockIdx.x * BM;
    if (m0 >= m_count) return;
    int n0 = blockIdx.y * BN;

    const float* B0 = B0g + (EXPERT ? (size_t)e * strideB : 0);
    const float* B1 = DUAL ? (B1g + (EXPERT ? (size_t)e * strideB : 0)) : nullptr;

    int tid = threadIdx.x;
    int lrow = tid >> 2;   // 0..63
    int lquad = tid & 3;   // 0..3

    int gr = m0 + lrow;
    bool rvalid = gr < m_count;
    size_t arow;
    if (GATHER) arow = rvalid ? (size_t)tok_of_row[m_base + gr] : 0;
    else        arow = (size_t)(EXPERT ? (m_base + gr) : gr);

    const float* Aptr  = A + arow * (size_t)K + lquad * 4;
    const float* B0ptr = B0 + (size_t)(n0 + lrow) * K + lquad * 4;
    const float* B1ptr = DUAL ? (B1 + (size_t)(n0 + lrow) * K + lquad * 4) : nullptr;

    int ty = tid >> 4, tx = tid & 15;
    float acc0[4][4] = {};
    float acc1[4][4] = {};

    for (int k0 = 0; k0 < K; k0 += BK) {
        float4 av = rvalid ? *(const float4*)(Aptr + k0) : make_float4(0.f, 0.f, 0.f, 0.f);
        float4 b0v = *(const float4*)(B0ptr + k0);
        const float* avp = (const float*)&av;
        const float* b0vp = (const float*)&b0v;
#pragma unroll
        for (int j = 0; j < 4; ++j) {
            As[lquad * 4 + j][lrow] = avp[j];
            Bs0[lquad * 4 + j][lrow] = b0vp[j];
        }
        if constexpr (DUAL) {
            float4 b1v = *(const float4*)(B1ptr + k0);
            const float* b1vp = (const float*)&b1v;
#pragma unroll
            for (int j = 0; j < 4; ++j) Bs1[lquad * 4 + j][lrow] = b1vp[j];
        }
        __syncthreads();

#pragma unroll
        for (int k = 0; k < BK; ++k) {
            float4 a = *(const float4*)&As[k][ty * 4];
            float4 b0 = *(const float4*)&Bs0[k][tx * 4];
            const float* ap = (const float*)&a;
            const float* bp = (const float*)&b0;
            if constexpr (DUAL) {
                float4 b1 = *(const float4*)&Bs1[k][tx * 4];
                const float* cp = (const float*)&b1;
#pragma unroll
                for (int i = 0; i < 4; ++i) {
#pragma unroll
                    for (int j = 0; j < 4; ++j) {
                        acc0[i][j] = fmaf(ap[i], bp[j], acc0[i][j]);
                        acc1[i][j] = fmaf(ap[i], cp[j], acc1[i][j]);
                    }
                }
            } else {
#pragma unroll
                for (int i = 0; i < 4; ++i)
#pragma unroll
                    for (int j = 0; j < 4; ++j)
                        acc0[i][j] = fmaf(ap[i], bp[j], acc0[i][j]);
            }
        }
        __syncthreads();
    }

#pragma unroll
    for (int i = 0; i < 4; ++i) {
        int gm = m0 + ty * 4 + i;
        if (gm >= m_count) continue;
        size_t crow = (size_t)(EXPERT ? (m_base + gm) : gm) * N + n0 + tx * 4;
#pragma unroll
        for (int j = 0; j < 4; ++j) {
            float v;
            if constexpr (SILU) {
                float g = acc0[i][j];
                float a = acc1[i][j];
                v = (g / (1.f + expf(-g))) * a;
            } else {
                v = acc0[i][j];
            }
            if constexpr (ACC) C[crow + j] += v;
            else               C[crow + j] = v;
        }
    }
}

// ---------------- combine: routed_lat[t] = w0*ex[row0] + w1*ex[row1] ----------------
__global__ void combine_kernel(const float* __restrict__ ex,
                               const int* __restrict__ row_of_pair,
                               const float* __restrict__ topk_w,
                               float* __restrict__ routed_lat)
{
    int i = blockIdx.x * blockDim.x + threadIdx.x;  // over T*L/4
    if (i >= T_TOK * L_LAT / 4) return;
    int t = i >> 6;               // L/4 = 64
    int l4 = (i & 63) * 4;
    int r0 = row_of_pair[2 * t], r1 = row_of_pair[2 * t + 1];
    float w0 = topk_w[2 * t], w1 = topk_w[2 * t + 1];
    float4 a = *(const float4*)(ex + (size_t)r0 * L_LAT + l4);
    float4 b = *(const float4*)(ex + (size_t)r1 * L_LAT + l4);
    float4 o;
    o.x = w0 * a.x + w1 * b.x;
    o.y = w0 * a.y + w1 * b.y;
    o.z = w0 * a.z + w1 * b.z;
    o.w = w0 * a.w + w1 * b.w;
    *(float4*)(routed_lat + (size_t)t * L_LAT + l4) = o;
}

extern "C" void kernel_launch(void* const* d_in, const int* in_sizes, int n_in,
                              void* d_out, int out_size, void* d_ws, size_t ws_size,
                              hipStream_t stream)
{
    const float* x        = (const float*)d_in[0];
    const float* w_router = (const float*)d_in[1];
    const float* w_down   = (const float*)d_in[2];
    const float* w_up     = (const float*)d_in[3];
    const float* w1_e     = (const float*)d_in[4];
    const float* wg_e     = (const float*)d_in[5];
    const float* w2_e     = (const float*)d_in[6];
    const float* w1_s     = (const float*)d_in[7];
    const float* wg_s     = (const float*)d_in[8];
    const float* w2_s     = (const float*)d_in[9];
    float* out = (float*)d_out;

    char* ws = (char*)d_ws;
    size_t off = 0;
    auto alloc = [&](size_t bytes) -> void* {
        void* p = ws + off;
        off += (bytes + 255) & ~(size_t)255;
        return p;
    };
    float* lat        = (float*)alloc((size_t)T_TOK * L_LAT * 4);        // 4 MB
    float* h1         = (float*)alloc((size_t)T_TOK * SH_HID * 4);       // 8 MB
    float* h_buf      = (float*)alloc((size_t)T_TOK * 2 * H_HID * 4);    // 16 MB
    float* ex         = (float*)alloc((size_t)T_TOK * 2 * L_LAT * 4);    // 8 MB
    float* routed_lat = (float*)alloc((size_t)T_TOK * L_LAT * 4);        // 4 MB
    int*   topk_idx   = (int*)alloc(T_TOK * 2 * 4);
    float* topk_w     = (float*)alloc(T_TOK * 2 * 4);
    int*   tok_of_row = (int*)alloc(T_TOK * 2 * 4);
    int*   row_of_pair= (int*)alloc(T_TOK * 2 * 4);
    int*   counts     = (int*)alloc(E_EXP * 4);
    int*   offsets    = (int*)alloc(E_EXP * 4);
    int*   cursor     = (int*)alloc(E_EXP * 4);

    dim3 blk(256);

    zero_counts_kernel<<<1, 64, 0, stream>>>(counts);
    router_kernel<<<T_TOK / 4, 256, 0, stream>>>(x, w_router, topk_idx, topk_w, counts);
    prep_kernel<<<1, 64, 0, stream>>>(counts, offsets, cursor);
    scatter_kernel<<<T_TOK / 256, 256, 0, stream>>>(topk_idx, cursor, tok_of_row, row_of_pair);

    // lat = x @ w_down^T         (M=T, N=L, K=D)
    gemm_nt<false, false, false, false, false>
        <<<dim3(T_TOK / BM, L_LAT / BN, 1), blk, 0, stream>>>(
        x, w_down, nullptr, lat, T_TOK, L_LAT, D_MODEL, nullptr, nullptr, nullptr, 0);

    // h1 = silu(x @ wg_s^T) * (x @ w1_s^T)   (M=T, N=SH, K=D)
    gemm_nt<true, true, false, false, false>
        <<<dim3(T_TOK / BM, SH_HID / BN, 1), blk, 0, stream>>>(
        x, wg_s, w1_s, h1, T_TOK, SH_HID, D_MODEL, nullptr, nullptr, nullptr, 0);

    // expert up (bucketed, gathered): h_buf = silu(lat@wg_e^T)*(lat@w1_e^T)
    gemm_nt<true, true, false, true, true>
        <<<dim3(2 * T_TOK / BM, H_HID / BN, E_EXP), blk, 0, stream>>>(
        lat, wg_e, w1_e, h_buf, 0, H_HID, L_LAT, tok_of_row, offsets, counts,
        (long)H_HID * L_LAT);

    // expert down: ex = h_buf @ w2_e^T (per expert)
    gemm_nt<false, false, false, true, false>
        <<<dim3(2 * T_TOK / BM, L_LAT / BN, E_EXP), blk, 0, stream>>>(
        h_buf, w2_e, nullptr, ex, 0, L_LAT, H_HID, nullptr, offsets, counts,
        (long)L_LAT * H_HID);

    // routed_lat[t] = w0*ex[row0] + w1*ex[row1]
    combine_kernel<<<(T_TOK * L_LAT / 4 + 255) / 256, 256, 0, stream>>>(
        ex, row_of_pair, topk_w, routed_lat);

    // out = routed_lat @ w_up^T   (M=T, N=D, K=L)
    gemm_nt<false, false, false, false, false>
        <<<dim3(T_TOK / BM, D_MODEL / BN, 1), blk, 0, stream>>>(
        routed_lat, w_up, nullptr, out, T_TOK, D_MODEL, L_LAT, nullptr, nullptr, nullptr, 0);

    // out += h1 @ w2_s^T          (M=T, N=D, K=SH)
    gemm_nt<false, false, true, false, false>
        <<<dim3(T_TOK / BM, D_MODEL / BN, 1), blk, 0, stream>>>(
        h1, w2_s, nullptr, out, T_TOK, D_MODEL, SH_HID, nullptr, nullptr, nullptr, 0);
}

// Round 2
// 276.378 us; speedup vs baseline: 2.1604x; 2.1604x over previous
//
#include <hip/hip_runtime.h>
#include <hip/hip_bf16.h>
#include <math.h>

#define T_TOK 4096
#define D_MODEL 1024
#define L_LAT 256
#define H_HID 512
#define E_EXP 8
#define SH_HID 512
#define KCAT 768           // L_LAT + SH_HID
#define TOT_EROWS (2 * T_TOK)

typedef __bf16 bf16x8 __attribute__((ext_vector_type(8)));
typedef float f32x4 __attribute__((ext_vector_type(4)));

__device__ __forceinline__ unsigned short f2bf(float f) {
    union { float f; unsigned int u; } c{f};
    unsigned int r = (c.u + 0x7fffu + ((c.u >> 16) & 1u)) >> 16;
    return (unsigned short)r;
}

__device__ __forceinline__ void gload_lds16(const unsigned short* g, unsigned short* l) {
    __builtin_amdgcn_global_load_lds(
        (const __attribute__((address_space(1))) void*)g,
        (__attribute__((address_space(3))) void*)l,
        16, 0, 0);
}

// XOR slot swizzle: spreads stride-64B rows across banks (2-way max, free)
__device__ __forceinline__ int swz(int row, int s) {
    return s ^ (row & 3) ^ ((row >> 2) & 3);
}

// ---------------- fused fp32->bf16 cast of x + all non-concat weights ----------------
// float4-index boundaries (compile-time): x 1048576 | w_down 65536 | wg_e 262144 |
// w1_e 262144 | w2_e 262144 | wg_s 131072 | w1_s 131072  => total 2162688 (8448 blocks)
__global__ void cast_all_kernel(const float* __restrict__ x, const float* __restrict__ w_down,
                                const float* __restrict__ wg_e, const float* __restrict__ w1_e,
                                const float* __restrict__ w2_e, const float* __restrict__ wg_s,
                                const float* __restrict__ w1_s,
                                unsigned short* __restrict__ xb, unsigned short* __restrict__ wdb,
                                unsigned short* __restrict__ wgeb, unsigned short* __restrict__ w1eb,
                                unsigned short* __restrict__ w2eb, unsigned short* __restrict__ wgsb,
                                unsigned short* __restrict__ w1sb)
{
    int i = blockIdx.x * 256 + threadIdx.x;
    const float* src; unsigned short* dst; int base;
    if      (i < 1048576) { src = x;      dst = xb;   base = 0; }
    else if (i < 1114112) { src = w_down; dst = wdb;  base = 1048576; }
    else if (i < 1376256) { src = wg_e;   dst = wgeb; base = 1114112; }
    else if (i < 1638400) { src = w1_e;   dst = w1eb; base = 1376256; }
    else if (i < 1900544) { src = w2_e;   dst = w2eb; base = 1638400; }
    else if (i < 2031616) { src = wg_s;   dst = wgsb; base = 1900544; }
    else                  { src = w1_s;   dst = w1sb; base = 2031616; }
    int j = (i - base) * 4;
    float4 v = *(const float4*)(src + j);
    ushort4 o = { f2bf(v.x), f2bf(v.y), f2bf(v.z), f2bf(v.w) };
    *(ushort4*)(dst + j) = o;
}

// wcat[d][0:256] = w_up[d][:], wcat[d][256:768] = w2_s[d][:]   (bf16)
__global__ void build_wcat_kernel(const float* __restrict__ w_up, const float* __restrict__ w2_s,
                                  unsigned short* __restrict__ wcat)
{
    int i = blockIdx.x * 256 + threadIdx.x;   // 196608 float4s
    int row = i / 192;
    int col = (i % 192) * 4;
    float4 v;
    if (col < 256) v = *(const float4*)(w_up + row * 256 + col);
    else           v = *(const float4*)(w2_s + row * 512 + (col - 256));
    ushort4 o = { f2bf(v.x), f2bf(v.y), f2bf(v.z), f2bf(v.w) };
    *(ushort4*)(wcat + row * KCAT + col) = o;
}

// ---------------- router (exact fp32) ----------------
__global__ void zero_counts_kernel(int* counts) {
    if (threadIdx.x < E_EXP) counts[threadIdx.x] = 0;
}

__global__ void router_kernel(const float* __restrict__ x,
                              const float* __restrict__ w_router,
                              int* __restrict__ topk_idx,
                              float* __restrict__ topk_w,
                              int* __restrict__ counts)
{
    int wid = threadIdx.x >> 6;
    int lane = threadIdx.x & 63;
    int t = blockIdx.x * 4 + wid;
    if (t >= T_TOK) return;
    const float* xr = x + (size_t)t * D_MODEL;

    float acc[E_EXP];
#pragma unroll
    for (int e = 0; e < E_EXP; ++e) acc[e] = 0.f;
    for (int i = 0; i < D_MODEL / 64; ++i) {
        int d = lane + i * 64;
        float xv = xr[d];
#pragma unroll
        for (int e = 0; e < E_EXP; ++e)
            acc[e] = fmaf(xv, w_router[e * D_MODEL + d], acc[e]);
    }
#pragma unroll
    for (int e = 0; e < E_EXP; ++e)
        for (int off = 32; off > 0; off >>= 1)
            acc[e] += __shfl_xor(acc[e], off, 64);
    if (lane == 0) {
        int i0 = 0; float v0 = acc[0];
#pragma unroll
        for (int e = 1; e < E_EXP; ++e) if (acc[e] > v0) { v0 = acc[e]; i0 = e; }
        int i1 = -1; float v1 = -INFINITY;
#pragma unroll
        for (int e = 0; e < E_EXP; ++e) if (e != i0 && acc[e] > v1) { v1 = acc[e]; i1 = e; }
        float e1 = expf(v1 - v0);
        float w0 = 1.f / (1.f + e1);
        float w1 = e1 / (1.f + e1);
        topk_idx[2 * t] = i0; topk_idx[2 * t + 1] = i1;
        topk_w[2 * t] = w0;  topk_w[2 * t + 1] = w1;
        atomicAdd(&counts[i0], 1);
        atomicAdd(&counts[i1], 1);
    }
}

__global__ void prep_kernel(const int* __restrict__ counts, int* __restrict__ offsets,
                            int* __restrict__ cursor)
{
    if (threadIdx.x == 0) {
        int acc = 0;
        for (int e = 0; e < E_EXP; ++e) { offsets[e] = acc; cursor[e] = acc; acc += counts[e]; }
    }
}

__global__ void scatter_kernel(const int* __restrict__ topk_idx, int* __restrict__ cursor,
                               int* __restrict__ tok_of_row, int* __restrict__ row_of_pair)
{
    int t = blockIdx.x * blockDim.x + threadIdx.x;
    if (t >= T_TOK) return;
#pragma unroll
    for (int s = 0; s < 2; ++s) {
        int e = topk_idx[2 * t + s];
        int p = atomicAdd(&cursor[e], 1);
        tok_of_row[p] = t;
        row_of_pair[2 * t + s] = p;
    }
}

// ---------------- bf16 MFMA NT GEMM ----------------
// A: [M][K] bf16 rowmajor, B: [N][K] bf16 rowmajor, C: MxN at ldc (+ccol)
// Tile 128 x BN_, BK=32, 4 waves (2x2). Wave computes 64 x (BN_/2).
// DUAL+SILU: C = silu(A@B0^T) * (A@B1^T). EXPERT: blockIdx.z bucket. GATHER: A row via tok_of_row.
template<int BN_, bool DUAL, bool SILU, bool EXPERT, bool GATHER, bool OUT_BF16>
__global__ __launch_bounds__(256)
void mfma_gemm(const unsigned short* __restrict__ A,
               const unsigned short* __restrict__ B0g,
               const unsigned short* __restrict__ B1g,
               void* __restrict__ Cv,
               int M, int N, int K, int ldc, int ccol,
               const int* __restrict__ tok_of_row,
               const int* __restrict__ offsets,
               const int* __restrict__ counts,
               long strideB)
{
    constexpr int NF = BN_ / 32;          // N-frags per wave
    constexpr int BR = BN_ / 64;          // staging rounds for B tile
    __shared__ __align__(16) unsigned short As[128 * 32];
    __shared__ __align__(16) unsigned short Bs0[BN_ * 32];
    __shared__ __align__(16) unsigned short Bs1[DUAL ? BN_ * 32 : 8];

    int e = EXPERT ? blockIdx.z : 0;
    int m_base = 0, m_count = M;
    if (EXPERT) { m_base = offsets[e]; m_count = counts[e]; }
    int m0 = blockIdx.x * 128;
    if (m0 >= m_count) return;
    int n0 = blockIdx.y * BN_;

    const unsigned short* B0 = B0g + (EXPERT ? (size_t)e * strideB : 0);
    const unsigned short* B1 = DUAL ? (B1g + (EXPERT ? (size_t)e * strideB : 0)) : nullptr;

    int tid = threadIdx.x;

    // staging source pointers (per-lane global, linear LDS dest, swizzled k-slot)
    const unsigned short* aptr[2];
#pragma unroll
    for (int r = 0; r < 2; ++r) {
        int trow = r * 64 + (tid >> 2);
        int mrow = m0 + trow;
        if (mrow >= m_count) mrow = m_count - 1;       // clamp (epilogue masks)
        long grow;
        if (GATHER)      grow = tok_of_row[m_base + mrow];
        else if (EXPERT) grow = m_base + mrow;
        else             grow = mrow;
        aptr[r] = A + (size_t)grow * K + swz(trow, tid & 3) * 8;
    }
    const unsigned short* bptr0[BR];
    const unsigned short* bptr1[BR];
#pragma unroll
    for (int r = 0; r < BR; ++r) {
        int trow = r * 64 + (tid >> 2);
        int gs = swz(trow, tid & 3) * 8;
        bptr0[r] = B0 + (size_t)(n0 + trow) * K + gs;
        if (DUAL) bptr1[r] = B1 + (size_t)(n0 + trow) * K + gs;
    }
    unsigned short* As_dst  = As  + tid * 8;
    unsigned short* Bs0_dst = Bs0 + tid * 8;
    unsigned short* Bs1_dst = DUAL ? (Bs1 + tid * 8) : nullptr;

    int wave = tid >> 6, lane = tid & 63;
    int wm0 = (wave >> 1) * 64;
    int wn0 = (wave & 1) * (BN_ / 2);
    int l15 = lane & 15, kg = lane >> 4;

    f32x4 acc0[4][NF] = {};
    f32x4 acc1[DUAL ? 4 : 1][DUAL ? NF : 1] = {};

    for (int k0 = 0; k0 < K; k0 += 32) {
#pragma unroll
        for (int r = 0; r < 2; ++r)
            gload_lds16(aptr[r] + k0, As_dst + r * 2048);
#pragma unroll
        for (int r = 0; r < BR; ++r) {
            gload_lds16(bptr0[r] + k0, Bs0_dst + r * 2048);
            if constexpr (DUAL) gload_lds16(bptr1[r] + k0, Bs1_dst + r * 2048);
        }
        __syncthreads();   // compiler drains vmcnt before barrier

        bf16x8 af[4];
#pragma unroll
        for (int mf = 0; mf < 4; ++mf) {
            int row = wm0 + mf * 16 + l15;
            af[mf] = *reinterpret_cast<const bf16x8*>(As + row * 32 + swz(row, kg) * 8);
        }
        bf16x8 bf0[NF], bf1[NF];
#pragma unroll
        for (int nf = 0; nf < NF; ++nf) {
            int row = wn0 + nf * 16 + l15;
            bf0[nf] = *reinterpret_cast<const bf16x8*>(Bs0 + row * 32 + swz(row, kg) * 8);
            if constexpr (DUAL)
                bf1[nf] = *reinterpret_cast<const bf16x8*>(Bs1 + row * 32 + swz(row, kg) * 8);
        }
#pragma unroll
        for (int mf = 0; mf < 4; ++mf)
#pragma unroll
            for (int nf = 0; nf < NF; ++nf) {
                acc0[mf][nf] = __builtin_amdgcn_mfma_f32_16x16x32_bf16(af[mf], bf0[nf], acc0[mf][nf], 0, 0, 0);
                if constexpr (DUAL)
                    acc1[mf][nf] = __builtin_amdgcn_mfma_f32_16x16x32_bf16(af[mf], bf1[nf], acc1[mf][nf], 0, 0, 0);
            }
        __syncthreads();
    }

    // epilogue: C/D layout col=lane&15, row=(lane>>4)*4+reg  [m89-verified]
#pragma unroll
    for (int mf = 0; mf < 4; ++mf) {
#pragma unroll
        for (int r4 = 0; r4 < 4; ++r4) {
            int mrow = m0 + wm0 + mf * 16 + kg * 4 + r4;
            if (mrow >= m_count) continue;
            size_t crow = (size_t)((EXPERT ? m_base : 0) + mrow) * ldc + ccol + n0 + wn0;
#pragma unroll
            for (int nf = 0; nf < NF; ++nf) {
                float v = acc0[mf][nf][r4];
                if constexpr (SILU) {
                    float g = v;
                    float a = acc1[mf][nf][r4];
                    v = (g / (1.f + expf(-g))) * a;
                }
                int col = nf * 16 + l15;
                if constexpr (OUT_BF16) ((unsigned short*)Cv)[crow + col] = f2bf(v);
                else                    ((float*)Cv)[crow + col] = v;
            }
        }
    }
}

// ---------------- combine: acat[t][0:256] = bf16(w0*ex[r0] + w1*ex[r1]) ----------------
__global__ void combine_kernel(const float* __restrict__ ex,
                               const int* __restrict__ row_of_pair,
                               const float* __restrict__ topk_w,
                               unsigned short* __restrict__ acat)
{
    int i = blockIdx.x * 256 + threadIdx.x;   // T*L/4 threads
    int t = i >> 6;
    int l4 = (i & 63) * 4;
    int r0 = row_of_pair[2 * t], r1 = row_of_pair[2 * t + 1];
    float w0 = topk_w[2 * t], w1 = topk_w[2 * t + 1];
    float4 a = *(const float4*)(ex + (size_t)r0 * L_LAT + l4);
    float4 b = *(const float4*)(ex + (size_t)r1 * L_LAT + l4);
    ushort4 o = { f2bf(w0 * a.x + w1 * b.x), f2bf(w0 * a.y + w1 * b.y),
                  f2bf(w0 * a.z + w1 * b.z), f2bf(w0 * a.w + w1 * b.w) };
    *(ushort4*)(acat + (size_t)t * KCAT + l4) = o;
}

extern "C" void kernel_launch(void* const* d_in, const int* in_sizes, int n_in,
                              void* d_out, int out_size, void* d_ws, size_t ws_size,
                              hipStream_t stream)
{
    const float* x        = (const float*)d_in[0];
    const float* w_router = (const float*)d_in[1];
    const float* w_down   = (const float*)d_in[2];
    const float* w_up     = (const float*)d_in[3];
    const float* w1_e     = (const float*)d_in[4];
    const float* wg_e     = (const float*)d_in[5];
    const float* w2_e     = (const float*)d_in[6];
    const float* w1_s     = (const float*)d_in[7];
    const float* wg_s     = (const float*)d_in[8];
    const float* w2_s     = (const float*)d_in[9];
    float* out = (float*)d_out;

    char* ws = (char*)d_ws;
    size_t off = 0;
    auto alloc = [&](size_t bytes) -> void* {
        void* p = ws + off;
        off += (bytes + 255) & ~(size_t)255;
        return p;
    };
    unsigned short* x_bf    = (unsigned short*)alloc((size_t)T_TOK * D_MODEL * 2);     // 8 MB
    unsigned short* lat_bf  = (unsigned short*)alloc((size_t)T_TOK * L_LAT * 2);       // 2 MB
    unsigned short* acat    = (unsigned short*)alloc((size_t)T_TOK * KCAT * 2);        // 6 MB
    float*          ex      = (float*)alloc((size_t)TOT_EROWS * L_LAT * 4);            // 8 MB
    unsigned short* wdown_bf= (unsigned short*)alloc((size_t)L_LAT * D_MODEL * 2);
    unsigned short* wge_bf  = (unsigned short*)alloc((size_t)E_EXP * H_HID * L_LAT * 2);
    unsigned short* w1e_bf  = (unsigned short*)alloc((size_t)E_EXP * H_HID * L_LAT * 2);
    unsigned short* w2e_bf  = (unsigned short*)alloc((size_t)E_EXP * L_LAT * H_HID * 2);
    unsigned short* wgs_bf  = (unsigned short*)alloc((size_t)SH_HID * D_MODEL * 2);
    unsigned short* w1s_bf  = (unsigned short*)alloc((size_t)SH_HID * D_MODEL * 2);
    unsigned short* wcat_bf = (unsigned short*)alloc((size_t)D_MODEL * KCAT * 2);
    int*   topk_idx    = (int*)alloc(T_TOK * 2 * 4);
    float* topk_w      = (float*)alloc(T_TOK * 2 * 4);
    int*   tok_of_row  = (int*)alloc(T_TOK * 2 * 4);
    int*   row_of_pair = (int*)alloc(T_TOK * 2 * 4);
    int*   counts      = (int*)alloc(E_EXP * 4);
    int*   offsets     = (int*)alloc(E_EXP * 4);
    int*   cursor      = (int*)alloc(E_EXP * 4);
    // h_buf aliases x_bf (x_bf dead after GEMM2; same 8 MB footprint)
    unsigned short* hbuf_bf = x_bf;

    // --- casts ---
    cast_all_kernel<<<8448, 256, 0, stream>>>(x, w_down, wg_e, w1_e, w2_e, wg_s, w1_s,
                                              x_bf, wdown_bf, wge_bf, w1e_bf, w2e_bf, wgs_bf, w1s_bf);
    build_wcat_kernel<<<768, 256, 0, stream>>>(w_up, w2_s, wcat_bf);

    // --- router ---
    zero_counts_kernel<<<1, 64, 0, stream>>>(counts);
    router_kernel<<<T_TOK / 4, 256, 0, stream>>>(x, w_router, topk_idx, topk_w, counts);
    prep_kernel<<<1, 64, 0, stream>>>(counts, offsets, cursor);
    scatter_kernel<<<T_TOK / 256, 256, 0, stream>>>(topk_idx, cursor, tok_of_row, row_of_pair);

    // --- GEMM1: lat = x @ w_down^T  (4096 x 256 x 1024) ---
    mfma_gemm<64, false, false, false, false, true>
        <<<dim3(T_TOK / 128, L_LAT / 64, 1), 256, 0, stream>>>(
        x_bf, wdown_bf, nullptr, lat_bf, T_TOK, L_LAT, D_MODEL, L_LAT, 0,
        nullptr, nullptr, nullptr, 0);

    // --- GEMM2: acat[:,256:768] = silu(x@wg_s^T)*(x@w1_s^T)  (4096 x 512 x 1024) ---
    mfma_gemm<64, true, true, false, false, true>
        <<<dim3(T_TOK / 128, SH_HID / 64, 1), 256, 0, stream>>>(
        x_bf, wgs_bf, w1s_bf, acat, T_TOK, SH_HID, D_MODEL, KCAT, L_LAT,
        nullptr, nullptr, nullptr, 0);

    // --- GEMM3: h_buf = silu(lat@wg_e^T)*(lat@w1_e^T)  (bucketed, gathered; N=512, K=256) ---
    mfma_gemm<64, true, true, true, true, true>
        <<<dim3(T_TOK / 128, H_HID / 64, E_EXP), 256, 0, stream>>>(
        lat_bf, wge_bf, w1e_bf, hbuf_bf, 0, H_HID, L_LAT, H_HID, 0,
        tok_of_row, offsets, counts, (long)H_HID * L_LAT);

    // --- GEMM4: ex = h_buf @ w2_e^T  (bucketed; N=256, K=512; fp32 out) ---
    mfma_gemm<64, false, false, true, false, false>
        <<<dim3(T_TOK / 128, L_LAT / 64, E_EXP), 256, 0, stream>>>(
        hbuf_bf, w2e_bf, nullptr, ex, 0, L_LAT, H_HID, L_LAT, 0,
        nullptr, offsets, counts, (long)L_LAT * H_HID);

    // --- combine -> acat[:,0:256] ---
    combine_kernel<<<T_TOK * L_LAT / 4 / 256, 256, 0, stream>>>(ex, row_of_pair, topk_w, acat);

    // --- GEMM5: out = acat @ wcat^T  (4096 x 1024 x 768; fp32 out) ---
    mfma_gemm<128, false, false, false, false, false>
        <<<dim3(T_TOK / 128, D_MODEL / 128, 1), 256, 0, stream>>>(
        acat, wcat_bf, nullptr, out, T_TOK, D_MODEL, KCAT, D_MODEL, 0,
        nullptr, nullptr, nullptr, 0);
}

// Round 3
// 160.619 us; speedup vs baseline: 3.7174x; 1.7207x over previous
//
#include <hip/hip_runtime.h>
#include <hip/hip_bf16.h>
#include <math.h>

#define T_TOK 4096
#define D_MODEL 1024
#define L_LAT 256
#define H_HID 512
#define E_EXP 8
#define SH_HID 512
#define KCAT 768           // L_LAT + SH_HID
#define TOT_EROWS (2 * T_TOK)

typedef __bf16 bf16x8 __attribute__((ext_vector_type(8)));
typedef float f32x4 __attribute__((ext_vector_type(4)));

__device__ __forceinline__ unsigned short f2bf(float f) {
    union { float f; unsigned int u; } c{f};
    unsigned int r = (c.u + 0x7fffu + ((c.u >> 16) & 1u)) >> 16;
    return (unsigned short)r;
}

__device__ __forceinline__ void gload_lds16(const unsigned short* g, unsigned short* l) {
    __builtin_amdgcn_global_load_lds(
        (const __attribute__((address_space(1))) void*)g,
        (__attribute__((address_space(3))) void*)l,
        16, 0, 0);
}

// XOR slot swizzle: spreads stride-64B rows across banks (2-way max, free)
__device__ __forceinline__ int swz(int row, int s) {
    return s ^ (row & 3) ^ ((row >> 2) & 3);
}

// ---------------- fused fp32->bf16 cast of x + all non-concat weights ----------------
__global__ void cast_all_kernel(const float* __restrict__ x, const float* __restrict__ w_down,
                                const float* __restrict__ wg_e, const float* __restrict__ w1_e,
                                const float* __restrict__ w2_e, const float* __restrict__ wg_s,
                                const float* __restrict__ w1_s,
                                unsigned short* __restrict__ xb, unsigned short* __restrict__ wdb,
                                unsigned short* __restrict__ wgeb, unsigned short* __restrict__ w1eb,
                                unsigned short* __restrict__ w2eb, unsigned short* __restrict__ wgsb,
                                unsigned short* __restrict__ w1sb)
{
    int i = blockIdx.x * 256 + threadIdx.x;
    const float* src; unsigned short* dst; int base;
    if      (i < 1048576) { src = x;      dst = xb;   base = 0; }
    else if (i < 1114112) { src = w_down; dst = wdb;  base = 1048576; }
    else if (i < 1376256) { src = wg_e;   dst = wgeb; base = 1114112; }
    else if (i < 1638400) { src = w1_e;   dst = w1eb; base = 1376256; }
    else if (i < 1900544) { src = w2_e;   dst = w2eb; base = 1638400; }
    else if (i < 2031616) { src = wg_s;   dst = wgsb; base = 1900544; }
    else                  { src = w1_s;   dst = w1sb; base = 2031616; }
    int j = (i - base) * 4;
    float4 v = *(const float4*)(src + j);
    ushort4 o = { f2bf(v.x), f2bf(v.y), f2bf(v.z), f2bf(v.w) };
    *(ushort4*)(dst + j) = o;
}

// wcat[d][0:256] = w_up[d][:], wcat[d][256:768] = w2_s[d][:]   (bf16)
__global__ void build_wcat_kernel(const float* __restrict__ w_up, const float* __restrict__ w2_s,
                                  unsigned short* __restrict__ wcat)
{
    int i = blockIdx.x * 256 + threadIdx.x;   // 196608 float4s
    int row = i / 192;
    int col = (i % 192) * 4;
    float4 v;
    if (col < 256) v = *(const float4*)(w_up + row * 256 + col);
    else           v = *(const float4*)(w2_s + row * 512 + (col - 256));
    ushort4 o = { f2bf(v.x), f2bf(v.y), f2bf(v.z), f2bf(v.w) };
    *(ushort4*)(wcat + row * KCAT + col) = o;
}

// ---------------- router (exact fp32, no atomics, w_router in LDS) ----------------
__global__ __launch_bounds__(256)
void router_kernel(const float* __restrict__ x, const float* __restrict__ w_router,
                   int* __restrict__ topk_idx, float* __restrict__ topk_w)
{
    __shared__ float wlds[E_EXP * D_MODEL];   // 32 KB
    int tid = threadIdx.x;
    for (int i = tid * 4; i < E_EXP * D_MODEL; i += 256 * 4)
        *(float4*)(wlds + i) = *(const float4*)(w_router + i);
    __syncthreads();

    int wid = tid >> 6, lane = tid & 63;
    int t = blockIdx.x * 4 + wid;
    const float* xr = x + (size_t)t * D_MODEL;

    float acc[E_EXP];
#pragma unroll
    for (int e = 0; e < E_EXP; ++e) acc[e] = 0.f;
#pragma unroll 4
    for (int i = 0; i < D_MODEL / 64; ++i) {
        int d = lane + i * 64;
        float xv = xr[d];
#pragma unroll
        for (int e = 0; e < E_EXP; ++e)
            acc[e] = fmaf(xv, wlds[e * D_MODEL + d], acc[e]);
    }
#pragma unroll
    for (int e = 0; e < E_EXP; ++e)
        for (int off = 32; off > 0; off >>= 1)
            acc[e] += __shfl_xor(acc[e], off, 64);
    if (lane == 0) {
        int i0 = 0; float v0 = acc[0];
#pragma unroll
        for (int e = 1; e < E_EXP; ++e) if (acc[e] > v0) { v0 = acc[e]; i0 = e; }
        int i1 = -1; float v1 = -INFINITY;
#pragma unroll
        for (int e = 0; e < E_EXP; ++e) if (e != i0 && acc[e] > v1) { v1 = acc[e]; i1 = e; }
        float e1 = expf(v1 - v0);
        float w0 = 1.f / (1.f + e1);
        float w1 = e1 / (1.f + e1);
        topk_idx[2 * t] = i0; topk_idx[2 * t + 1] = i1;
        topk_w[2 * t] = w0;  topk_w[2 * t + 1] = w1;
    }
}

// ---------------- deterministic bucket build: counts/offsets/ranks, NO atomics ----------
// One block, 1024 threads, 8 items each (item i = token i>>1, slot i&1).
__global__ __launch_bounds__(1024)
void bucket_kernel(const int* __restrict__ topk_idx,
                   int* __restrict__ counts, int* __restrict__ offsets,
                   int* __restrict__ tok_of_row, int* __restrict__ row_of_pair)
{
    __shared__ int s_wavecnt[16][E_EXP];
    __shared__ int s_wavebase[16][E_EXP];
    __shared__ int s_tot[E_EXP];
    __shared__ int s_off[E_EXP];

    int tid = threadIdx.x;
    int wave = tid >> 6, lane = tid & 63;
    int base_i = tid * 8;

    int e_loc[8];
    int cnt[E_EXP];
#pragma unroll
    for (int e = 0; e < E_EXP; ++e) cnt[e] = 0;
#pragma unroll
    for (int j = 0; j < 8; ++j) {
        int e = topk_idx[base_i + j];
        e_loc[j] = e;
#pragma unroll
        for (int q = 0; q < E_EXP; ++q) cnt[q] += (e == q) ? 1 : 0;
    }

    int excl[E_EXP];
#pragma unroll
    for (int e = 0; e < E_EXP; ++e) {
        int v = cnt[e];
#pragma unroll
        for (int off = 1; off < 64; off <<= 1) {
            int u = __shfl_up(v, off, 64);
            v += (lane >= off) ? u : 0;
        }
        excl[e] = v - cnt[e];
        if (lane == 63) s_wavecnt[wave][e] = v;
    }
    __syncthreads();

    if (tid < E_EXP) {
        int tot = 0;
        for (int w = 0; w < 16; ++w) tot += s_wavecnt[w][tid];
        s_tot[tid] = tot;
        counts[tid] = tot;
    }
    __syncthreads();
    if (tid == 0) {
        int off = 0;
        for (int e = 0; e < E_EXP; ++e) { s_off[e] = off; offsets[e] = off; off += s_tot[e]; }
    }
    __syncthreads();
    if (tid < E_EXP) {
        int run = s_off[tid];
        for (int w = 0; w < 16; ++w) { s_wavebase[w][tid] = run; run += s_wavecnt[w][tid]; }
    }
    __syncthreads();

    int tb[E_EXP];
#pragma unroll
    for (int e = 0; e < E_EXP; ++e) tb[e] = s_wavebase[wave][e] + excl[e];
#pragma unroll
    for (int j = 0; j < 8; ++j) {
        int e = e_loc[j];
        int p = 0;
#pragma unroll
        for (int q = 0; q < E_EXP; ++q) if (e == q) { p = tb[q]; tb[q] = p + 1; }
        int item = base_i + j;
        tok_of_row[p] = item >> 1;
        row_of_pair[item] = p;
    }
}

// ---------------- bf16 MFMA NT GEMM ----------------
template<int BN_, bool DUAL, bool SILU, bool EXPERT, bool GATHER, bool OUT_BF16>
__global__ __launch_bounds__(256)
void mfma_gemm(const unsigned short* __restrict__ A,
               const unsigned short* __restrict__ B0g,
               const unsigned short* __restrict__ B1g,
               void* __restrict__ Cv,
               int M, int N, int K, int ldc, int ccol,
               const int* __restrict__ tok_of_row,
               const int* __restrict__ offsets,
               const int* __restrict__ counts,
               long strideB)
{
    constexpr int NF = BN_ / 32;
    constexpr int BR = BN_ / 64;
    __shared__ __align__(16) unsigned short As[128 * 32];
    __shared__ __align__(16) unsigned short Bs0[BN_ * 32];
    __shared__ __align__(16) unsigned short Bs1[DUAL ? BN_ * 32 : 8];

    int e = EXPERT ? blockIdx.z : 0;
    int m_base = 0, m_count = M;
    if (EXPERT) { m_base = offsets[e]; m_count = counts[e]; }
    int m0 = blockIdx.x * 128;
    if (m0 >= m_count) return;
    int n0 = blockIdx.y * BN_;

    const unsigned short* B0 = B0g + (EXPERT ? (size_t)e * strideB : 0);
    const unsigned short* B1 = DUAL ? (B1g + (EXPERT ? (size_t)e * strideB : 0)) : nullptr;

    int tid = threadIdx.x;

    const unsigned short* aptr[2];
#pragma unroll
    for (int r = 0; r < 2; ++r) {
        int trow = r * 64 + (tid >> 2);
        int mrow = m0 + trow;
        if (mrow >= m_count) mrow = m_count - 1;
        long grow;
        if (GATHER)      grow = tok_of_row[m_base + mrow];
        else if (EXPERT) grow = m_base + mrow;
        else             grow = mrow;
        aptr[r] = A + (size_t)grow * K + swz(trow, tid & 3) * 8;
    }
    const unsigned short* bptr0[BR];
    const unsigned short* bptr1[BR];
#pragma unroll
    for (int r = 0; r < BR; ++r) {
        int trow = r * 64 + (tid >> 2);
        int gs = swz(trow, tid & 3) * 8;
        bptr0[r] = B0 + (size_t)(n0 + trow) * K + gs;
        if (DUAL) bptr1[r] = B1 + (size_t)(n0 + trow) * K + gs;
    }
    unsigned short* As_dst  = As  + tid * 8;
    unsigned short* Bs0_dst = Bs0 + tid * 8;
    unsigned short* Bs1_dst = DUAL ? (Bs1 + tid * 8) : nullptr;

    int wave = tid >> 6, lane = tid & 63;
    int wm0 = (wave >> 1) * 64;
    int wn0 = (wave & 1) * (BN_ / 2);
    int l15 = lane & 15, kg = lane >> 4;

    f32x4 acc0[4][NF] = {};
    f32x4 acc1[DUAL ? 4 : 1][DUAL ? NF : 1] = {};

    for (int k0 = 0; k0 < K; k0 += 32) {
#pragma unroll
        for (int r = 0; r < 2; ++r)
            gload_lds16(aptr[r] + k0, As_dst + r * 2048);
#pragma unroll
        for (int r = 0; r < BR; ++r) {
            gload_lds16(bptr0[r] + k0, Bs0_dst + r * 2048);
            if constexpr (DUAL) gload_lds16(bptr1[r] + k0, Bs1_dst + r * 2048);
        }
        __syncthreads();

        bf16x8 af[4];
#pragma unroll
        for (int mf = 0; mf < 4; ++mf) {
            int row = wm0 + mf * 16 + l15;
            af[mf] = *reinterpret_cast<const bf16x8*>(As + row * 32 + swz(row, kg) * 8);
        }
        bf16x8 bf0[NF], bf1[NF];
#pragma unroll
        for (int nf = 0; nf < NF; ++nf) {
            int row = wn0 + nf * 16 + l15;
            bf0[nf] = *reinterpret_cast<const bf16x8*>(Bs0 + row * 32 + swz(row, kg) * 8);
            if constexpr (DUAL)
                bf1[nf] = *reinterpret_cast<const bf16x8*>(Bs1 + row * 32 + swz(row, kg) * 8);
        }
#pragma unroll
        for (int mf = 0; mf < 4; ++mf)
#pragma unroll
            for (int nf = 0; nf < NF; ++nf) {
                acc0[mf][nf] = __builtin_amdgcn_mfma_f32_16x16x32_bf16(af[mf], bf0[nf], acc0[mf][nf], 0, 0, 0);
                if constexpr (DUAL)
                    acc1[mf][nf] = __builtin_amdgcn_mfma_f32_16x16x32_bf16(af[mf], bf1[nf], acc1[mf][nf], 0, 0, 0);
            }
        __syncthreads();
    }

#pragma unroll
    for (int mf = 0; mf < 4; ++mf) {
#pragma unroll
        for (int r4 = 0; r4 < 4; ++r4) {
            int mrow = m0 + wm0 + mf * 16 + kg * 4 + r4;
            if (mrow >= m_count) continue;
            size_t crow = (size_t)((EXPERT ? m_base : 0) + mrow) * ldc + ccol + n0 + wn0;
#pragma unroll
            for (int nf = 0; nf < NF; ++nf) {
                float v = acc0[mf][nf][r4];
                if constexpr (SILU) {
                    float g = v;
                    float a = acc1[mf][nf][r4];
                    v = (g / (1.f + expf(-g))) * a;
                }
                int col = nf * 16 + l15;
                if constexpr (OUT_BF16) ((unsigned short*)Cv)[crow + col] = f2bf(v);
                else                    ((float*)Cv)[crow + col] = v;
            }
        }
    }
}

// ---------------- combine: acat[t][0:256] = bf16(w0*ex[r0] + w1*ex[r1]) ----------------
__global__ void combine_kernel(const float* __restrict__ ex,
                               const int* __restrict__ row_of_pair,
                               const float* __restrict__ topk_w,
                               unsigned short* __restrict__ acat)
{
    int i = blockIdx.x * 256 + threadIdx.x;
    int t = i >> 6;
    int l4 = (i & 63) * 4;
    int r0 = row_of_pair[2 * t], r1 = row_of_pair[2 * t + 1];
    float w0 = topk_w[2 * t], w1 = topk_w[2 * t + 1];
    float4 a = *(const float4*)(ex + (size_t)r0 * L_LAT + l4);
    float4 b = *(const float4*)(ex + (size_t)r1 * L_LAT + l4);
    ushort4 o = { f2bf(w0 * a.x + w1 * b.x), f2bf(w0 * a.y + w1 * b.y),
                  f2bf(w0 * a.z + w1 * b.z), f2bf(w0 * a.w + w1 * b.w) };
    *(ushort4*)(acat + (size_t)t * KCAT + l4) = o;
}

extern "C" void kernel_launch(void* const* d_in, const int* in_sizes, int n_in,
                              void* d_out, int out_size, void* d_ws, size_t ws_size,
                              hipStream_t stream)
{
    const float* x        = (const float*)d_in[0];
    const float* w_router = (const float*)d_in[1];
    const float* w_down   = (const float*)d_in[2];
    const float* w_up     = (const float*)d_in[3];
    const float* w1_e     = (const float*)d_in[4];
    const float* wg_e     = (const float*)d_in[5];
    const float* w2_e     = (const float*)d_in[6];
    const float* w1_s     = (const float*)d_in[7];
    const float* wg_s     = (const float*)d_in[8];
    const float* w2_s     = (const float*)d_in[9];
    float* out = (float*)d_out;

    char* ws = (char*)d_ws;
    size_t off = 0;
    auto alloc = [&](size_t bytes) -> void* {
        void* p = ws + off;
        off += (bytes + 255) & ~(size_t)255;
        return p;
    };
    unsigned short* x_bf    = (unsigned short*)alloc((size_t)T_TOK * D_MODEL * 2);
    unsigned short* lat_bf  = (unsigned short*)alloc((size_t)T_TOK * L_LAT * 2);
    unsigned short* acat    = (unsigned short*)alloc((size_t)T_TOK * KCAT * 2);
    float*          ex      = (float*)alloc((size_t)TOT_EROWS * L_LAT * 4);
    unsigned short* wdown_bf= (unsigned short*)alloc((size_t)L_LAT * D_MODEL * 2);
    unsigned short* wge_bf  = (unsigned short*)alloc((size_t)E_EXP * H_HID * L_LAT * 2);
    unsigned short* w1e_bf  = (unsigned short*)alloc((size_t)E_EXP * H_HID * L_LAT * 2);
    unsigned short* w2e_bf  = (unsigned short*)alloc((size_t)E_EXP * L_LAT * H_HID * 2);
    unsigned short* wgs_bf  = (unsigned short*)alloc((size_t)SH_HID * D_MODEL * 2);
    unsigned short* w1s_bf  = (unsigned short*)alloc((size_t)SH_HID * D_MODEL * 2);
    unsigned short* wcat_bf = (unsigned short*)alloc((size_t)D_MODEL * KCAT * 2);
    int*   topk_idx    = (int*)alloc(T_TOK * 2 * 4);
    float* topk_w      = (float*)alloc(T_TOK * 2 * 4);
    int*   tok_of_row  = (int*)alloc(T_TOK * 2 * 4);
    int*   row_of_pair = (int*)alloc(T_TOK * 2 * 4);
    int*   counts      = (int*)alloc(E_EXP * 4);
    int*   offsets     = (int*)alloc(E_EXP * 4);
    unsigned short* hbuf_bf = x_bf;   // alias: x_bf dead after GEMM2

    cast_all_kernel<<<8448, 256, 0, stream>>>(x, w_down, wg_e, w1_e, w2_e, wg_s, w1_s,
                                              x_bf, wdown_bf, wge_bf, w1e_bf, w2e_bf, wgs_bf, w1s_bf);
    build_wcat_kernel<<<768, 256, 0, stream>>>(w_up, w2_s, wcat_bf);

    router_kernel<<<T_TOK / 4, 256, 0, stream>>>(x, w_router, topk_idx, topk_w);
    bucket_kernel<<<1, 1024, 0, stream>>>(topk_idx, counts, offsets, tok_of_row, row_of_pair);

    // GEMM1: lat = x @ w_down^T  (4096 x 256 x 1024)
    mfma_gemm<64, false, false, false, false, true>
        <<<dim3(T_TOK / 128, L_LAT / 64, 1), 256, 0, stream>>>(
        x_bf, wdown_bf, nullptr, lat_bf, T_TOK, L_LAT, D_MODEL, L_LAT, 0,
        nullptr, nullptr, nullptr, 0);

    // GEMM2: acat[:,256:768] = silu(x@wg_s^T)*(x@w1_s^T)  (4096 x 512 x 1024)
    mfma_gemm<64, true, true, false, false, true>
        <<<dim3(T_TOK / 128, SH_HID / 64, 1), 256, 0, stream>>>(
        x_bf, wgs_bf, w1s_bf, acat, T_TOK, SH_HID, D_MODEL, KCAT, L_LAT,
        nullptr, nullptr, nullptr, 0);

    // GEMM3: h_buf = silu(lat@wg_e^T)*(lat@w1_e^T)  (bucketed, gathered; N=512, K=256)
    mfma_gemm<64, true, true, true, true, true>
        <<<dim3(TOT_EROWS / 128, H_HID / 64, E_EXP), 256, 0, stream>>>(
        lat_bf, wge_bf, w1e_bf, hbuf_bf, 0, H_HID, L_LAT, H_HID, 0,
        tok_of_row, offsets, counts, (long)H_HID * L_LAT);

    // GEMM4: ex = h_buf @ w2_e^T  (bucketed; N=256, K=512; fp32 out)
    mfma_gemm<64, false, false, true, false, false>
        <<<dim3(TOT_EROWS / 128, L_LAT / 64, E_EXP), 256, 0, stream>>>(
        hbuf_bf, w2e_bf, nullptr, ex, 0, L_LAT, H_HID, L_LAT, 0,
        nullptr, offsets, counts, (long)L_LAT * H_HID);

    combine_kernel<<<T_TOK * L_LAT / 4 / 256, 256, 0, stream>>>(ex, row_of_pair, topk_w, acat);

    // GEMM5: out = acat @ wcat^T  (4096 x 1024 x 768; fp32 out)
    mfma_gemm<128, false, false, false, false, false>
        <<<dim3(T_TOK / 128, D_MODEL / 128, 1), 256, 0, stream>>>(
        acat, wcat_bf, nullptr, out, T_TOK, D_MODEL, KCAT, D_MODEL, 0,
        nullptr, nullptr, nullptr, 0);
}

// Round 5
// 135.581 us; speedup vs baseline: 4.4040x; 1.1847x over previous
//
#include <hip/hip_runtime.h>
#include <hip/hip_bf16.h>
#include <math.h>

#define T_TOK 4096
#define D_MODEL 1024
#define L_LAT 256
#define H_HID 512
#define E_EXP 8
#define SH_HID 512
#define KCAT 768
#define TOT_EROWS (2 * T_TOK)

typedef __bf16 bf16x8 __attribute__((ext_vector_type(8)));
typedef float f32x4 __attribute__((ext_vector_type(4)));

__device__ __forceinline__ unsigned short f2bf(float f) {
    union { float f; unsigned int u; } c{f};
    unsigned int r = (c.u + 0x7fffu + ((c.u >> 16) & 1u)) >> 16;
    return (unsigned short)r;
}

__device__ __forceinline__ void gload_lds16(const unsigned short* g, unsigned short* l) {
    __builtin_amdgcn_global_load_lds(
        (const __attribute__((address_space(1))) void*)g,
        (__attribute__((address_space(3))) void*)l,
        16, 0, 0);
}

// XOR slot swizzle (involution over s in [0,4))
__device__ __forceinline__ int swz(int row, int s) {
    return s ^ (row & 3) ^ ((row >> 2) & 3);
}

// ================= dispatch 1: casts + wcat + router (jobs) =================
// blocks [0,8448): cast 7 tensors; [8448,9216): build wcat; [9216,10240): router
__global__ __launch_bounds__(256)
void cast_router_kernel(const float* __restrict__ x, const float* __restrict__ w_down,
                        const float* __restrict__ wg_e, const float* __restrict__ w1_e,
                        const float* __restrict__ w2_e, const float* __restrict__ wg_s,
                        const float* __restrict__ w1_s, const float* __restrict__ w_up,
                        const float* __restrict__ w2_s, const float* __restrict__ w_router,
                        unsigned short* __restrict__ xb, unsigned short* __restrict__ wdb,
                        unsigned short* __restrict__ wgeb, unsigned short* __restrict__ w1eb,
                        unsigned short* __restrict__ w2eb, unsigned short* __restrict__ wgsb,
                        unsigned short* __restrict__ w1sb, unsigned short* __restrict__ wcat,
                        int* __restrict__ topk_idx, float* __restrict__ topk_w)
{
    __shared__ float wlds[E_EXP * D_MODEL];   // 32 KB (router job only)
    int bid = blockIdx.x;
    int tid = threadIdx.x;

    if (bid < 8448) {
        int i = bid * 256 + tid;
        const float* src; unsigned short* dst; int base;
        if      (i < 1048576) { src = x;      dst = xb;   base = 0; }
        else if (i < 1114112) { src = w_down; dst = wdb;  base = 1048576; }
        else if (i < 1376256) { src = wg_e;   dst = wgeb; base = 1114112; }
        else if (i < 1638400) { src = w1_e;   dst = w1eb; base = 1376256; }
        else if (i < 1900544) { src = w2_e;   dst = w2eb; base = 1638400; }
        else if (i < 2031616) { src = wg_s;   dst = wgsb; base = 1900544; }
        else                  { src = w1_s;   dst = w1sb; base = 2031616; }
        int j = (i - base) * 4;
        float4 v = *(const float4*)(src + j);
        ushort4 o = { f2bf(v.x), f2bf(v.y), f2bf(v.z), f2bf(v.w) };
        *(ushort4*)(dst + j) = o;
        return;
    }
    if (bid < 9216) {
        int i = (bid - 8448) * 256 + tid;    // 196608 float4s
        int row = i / 192;
        int col = (i % 192) * 4;
        float4 v;
        if (col < 256) v = *(const float4*)(w_up + row * 256 + col);
        else           v = *(const float4*)(w2_s + row * 512 + (col - 256));
        ushort4 o = { f2bf(v.x), f2bf(v.y), f2bf(v.z), f2bf(v.w) };
        *(ushort4*)(wcat + row * KCAT + col) = o;
        return;
    }

    // ---- router job (exact fp32) ----
    int rb = bid - 9216;
    for (int i = tid * 4; i < E_EXP * D_MODEL; i += 256 * 4)
        *(float4*)(wlds + i) = *(const float4*)(w_router + i);
    __syncthreads();

    int wid = tid >> 6, lane = tid & 63;
    int t = rb * 4 + wid;
    const float* xr = x + (size_t)t * D_MODEL;
    float acc[E_EXP];
#pragma unroll
    for (int e = 0; e < E_EXP; ++e) acc[e] = 0.f;
#pragma unroll 4
    for (int i = 0; i < D_MODEL / 64; ++i) {
        int d = lane + i * 64;
        float xv = xr[d];
#pragma unroll
        for (int e = 0; e < E_EXP; ++e)
            acc[e] = fmaf(xv, wlds[e * D_MODEL + d], acc[e]);
    }
#pragma unroll
    for (int e = 0; e < E_EXP; ++e)
        for (int off = 32; off > 0; off >>= 1)
            acc[e] += __shfl_xor(acc[e], off, 64);
    if (lane == 0) {
        int i0 = 0; float v0 = acc[0];
#pragma unroll
        for (int e = 1; e < E_EXP; ++e) if (acc[e] > v0) { v0 = acc[e]; i0 = e; }
        int i1 = -1; float v1 = -INFINITY;
#pragma unroll
        for (int e = 0; e < E_EXP; ++e) if (e != i0 && acc[e] > v1) { v1 = acc[e]; i1 = e; }
        float e1 = expf(v1 - v0);
        topk_idx[2 * t] = i0; topk_idx[2 * t + 1] = i1;
        topk_w[2 * t] = 1.f / (1.f + e1);
        topk_w[2 * t + 1] = e1 / (1.f + e1);
    }
}

// ================= bucket body (deterministic, no atomics; 256 threads) =========
__device__ void bucket_body(const int* __restrict__ topk_idx,
                            int* __restrict__ counts, int* __restrict__ offsets,
                            int* __restrict__ tok_of_row, int* __restrict__ row_of_pair,
                            int* sb)
{
    int* s_wavecnt  = sb;        // [4][8]
    int* s_wavebase = sb + 32;   // [4][8]
    int* s_tot      = sb + 64;   // [8]
    int* s_off      = sb + 72;   // [8]
    int tid = threadIdx.x, wave = tid >> 6, lane = tid & 63;
    int base_i = tid * 32;       // 8192 items / 256 threads

    int cnt[E_EXP];
#pragma unroll
    for (int e = 0; e < E_EXP; ++e) cnt[e] = 0;
#pragma unroll
    for (int j = 0; j < 32; ++j) {
        int e = topk_idx[base_i + j];
#pragma unroll
        for (int q = 0; q < E_EXP; ++q) cnt[q] += (e == q) ? 1 : 0;
    }
    int excl[E_EXP];
#pragma unroll
    for (int e = 0; e < E_EXP; ++e) {
        int v = cnt[e];
#pragma unroll
        for (int off = 1; off < 64; off <<= 1) {
            int u = __shfl_up(v, off, 64);
            v += (lane >= off) ? u : 0;
        }
        excl[e] = v - cnt[e];
        if (lane == 63) s_wavecnt[wave * 8 + e] = v;
    }
    __syncthreads();
    if (tid < E_EXP) {
        int tot = 0;
        for (int w = 0; w < 4; ++w) tot += s_wavecnt[w * 8 + tid];
        s_tot[tid] = tot;
        counts[tid] = tot;
    }
    __syncthreads();
    if (tid == 0) {
        int off = 0;
        for (int e = 0; e < E_EXP; ++e) { s_off[e] = off; offsets[e] = off; off += s_tot[e]; }
    }
    __syncthreads();
    if (tid < E_EXP) {
        int run = s_off[tid];
        for (int w = 0; w < 4; ++w) { s_wavebase[w * 8 + tid] = run; run += s_wavecnt[w * 8 + tid]; }
    }
    __syncthreads();
    int tb[E_EXP];
#pragma unroll
    for (int e = 0; e < E_EXP; ++e) tb[e] = s_wavebase[wave * 8 + e] + excl[e];
#pragma unroll
    for (int j = 0; j < 32; ++j) {
        int item = base_i + j;
        int e = topk_idx[item];
        int p = 0;
#pragma unroll
        for (int q = 0; q < E_EXP; ++q) if (e == q) { p = tb[q]; tb[q] = p + 1; }
        tok_of_row[p] = item >> 1;
        row_of_pair[item] = p;
    }
}

// ================= dispatch 2: GEMM1 + GEMM2 + bucket (jobs) =================
// y in [0,4): GEMM1 lat = x@w_down^T (N=256). y in [4,12): GEMM2 acat[:,256:768] (N=512).
// y == 12, x == 0: bucket.
__global__ __launch_bounds__(256)
void k_main(const unsigned short* __restrict__ x_bf,
            const unsigned short* __restrict__ wdown_bf,
            const unsigned short* __restrict__ wgs_bf,
            const unsigned short* __restrict__ w1s_bf,
            unsigned short* __restrict__ lat_bf,
            unsigned short* __restrict__ acat,
            const int* __restrict__ topk_idx,
            int* __restrict__ counts, int* __restrict__ offsets,
            int* __restrict__ tok_of_row, int* __restrict__ row_of_pair)
{
    __shared__ __align__(16) unsigned short As[128 * 32];
    __shared__ __align__(16) unsigned short Bs0[64 * 32];
    __shared__ __align__(16) unsigned short Bs1[64 * 32];

    int y = blockIdx.y;
    if (y == 12) {
        if (blockIdx.x == 0)
            bucket_body(topk_idx, counts, offsets, tok_of_row, row_of_pair, (int*)As);
        return;
    }
    bool dual = (y >= 4);
    int n0 = dual ? (y - 4) * 64 : y * 64;
    const unsigned short* B0 = dual ? wgs_bf : wdown_bf;
    unsigned short* C = dual ? (acat + L_LAT) : lat_bf;   // GEMM2 -> acat cols 256:768
    int ldc = dual ? KCAT : L_LAT;

    int m0 = blockIdx.x * 128;
    int tid = threadIdx.x;
    int trow = tid >> 2, slot = tid & 3;
    int csw = swz(trow, slot) * 8;   // same for row and row+64

    const unsigned short* aptr0 = x_bf + (size_t)(m0 + trow) * D_MODEL + csw;
    const unsigned short* aptr1 = x_bf + (size_t)(m0 + 64 + trow) * D_MODEL + csw;
    const unsigned short* bptr0 = B0 + (size_t)(n0 + trow) * D_MODEL + csw;
    const unsigned short* bptr1 = w1s_bf + (size_t)(n0 + trow) * D_MODEL + csw;
    unsigned short* As_dst  = As  + tid * 8;
    unsigned short* Bs0_dst = Bs0 + tid * 8;
    unsigned short* Bs1_dst = Bs1 + tid * 8;

    int wave = tid >> 6, lane = tid & 63;
    int wm0 = (wave >> 1) * 64, wn0 = (wave & 1) * 32;
    int l15 = lane & 15, kg = lane >> 4;

    f32x4 acc0[4][2] = {};
    f32x4 acc1[4][2] = {};

    for (int k0 = 0; k0 < D_MODEL; k0 += 32) {
        gload_lds16(aptr0 + k0, As_dst);
        gload_lds16(aptr1 + k0, As_dst + 2048);
        gload_lds16(bptr0 + k0, Bs0_dst);
        if (dual) gload_lds16(bptr1 + k0, Bs1_dst);
        __syncthreads();

        bf16x8 af[4];
#pragma unroll
        for (int mf = 0; mf < 4; ++mf) {
            int row = wm0 + mf * 16 + l15;
            af[mf] = *reinterpret_cast<const bf16x8*>(As + row * 32 + swz(row, kg) * 8);
        }
        bf16x8 bf0[2], bf1[2];
#pragma unroll
        for (int nf = 0; nf < 2; ++nf) {
            int row = wn0 + nf * 16 + l15;
            bf0[nf] = *reinterpret_cast<const bf16x8*>(Bs0 + row * 32 + swz(row, kg) * 8);
        }
        if (dual) {
#pragma unroll
            for (int nf = 0; nf < 2; ++nf) {
                int row = wn0 + nf * 16 + l15;
                bf1[nf] = *reinterpret_cast<const bf16x8*>(Bs1 + row * 32 + swz(row, kg) * 8);
            }
        }
#pragma unroll
        for (int mf = 0; mf < 4; ++mf)
#pragma unroll
            for (int nf = 0; nf < 2; ++nf)
                acc0[mf][nf] = __builtin_amdgcn_mfma_f32_16x16x32_bf16(af[mf], bf0[nf], acc0[mf][nf], 0, 0, 0);
        if (dual) {
#pragma unroll
            for (int mf = 0; mf < 4; ++mf)
#pragma unroll
                for (int nf = 0; nf < 2; ++nf)
                    acc1[mf][nf] = __builtin_amdgcn_mfma_f32_16x16x32_bf16(af[mf], bf1[nf], acc1[mf][nf], 0, 0, 0);
        }
        __syncthreads();
    }

#pragma unroll
    for (int mf = 0; mf < 4; ++mf)
#pragma unroll
        for (int r4 = 0; r4 < 4; ++r4) {
            int mrow = m0 + wm0 + mf * 16 + kg * 4 + r4;
            size_t crow = (size_t)mrow * ldc + n0 + wn0;
#pragma unroll
            for (int nf = 0; nf < 2; ++nf) {
                float v = acc0[mf][nf][r4];
                if (dual) {
                    float g = v, a = acc1[mf][nf][r4];
                    v = (g / (1.f + expf(-g))) * a;
                }
                C[crow + nf * 16 + l15] = f2bf(v);
            }
        }
}

// ================= dispatches 3/4/6: proven MFMA NT GEMM template ==============
template<int BN_, bool DUAL, bool SILU, bool EXPERT, bool GATHER, bool OUT_BF16>
__global__ __launch_bounds__(256)
void mfma_gemm(const unsigned short* __restrict__ A,
               const unsigned short* __restrict__ B0g,
               const unsigned short* __restrict__ B1g,
               void* __restrict__ Cv,
               int M, int N, int K, int ldc, int ccol,
               const int* __restrict__ tok_of_row,
               const int* __restrict__ offsets,
               const int* __restrict__ counts,
               long strideB)
{
    constexpr int NF = BN_ / 32;
    constexpr int BR = BN_ / 64;
    __shared__ __align__(16) unsigned short As[128 * 32];
    __shared__ __align__(16) unsigned short Bs0[BN_ * 32];
    __shared__ __align__(16) unsigned short Bs1[DUAL ? BN_ * 32 : 8];

    int e = EXPERT ? blockIdx.z : 0;
    int m_base = 0, m_count = M;
    if (EXPERT) { m_base = offsets[e]; m_count = counts[e]; }
    int m0 = blockIdx.x * 128;
    if (m0 >= m_count) return;
    int n0 = blockIdx.y * BN_;

    const unsigned short* B0 = B0g + (EXPERT ? (size_t)e * strideB : 0);
    const unsigned short* B1 = DUAL ? (B1g + (EXPERT ? (size_t)e * strideB : 0)) : nullptr;

    int tid = threadIdx.x;
    const unsigned short* aptr[2];
#pragma unroll
    for (int r = 0; r < 2; ++r) {
        int trow = r * 64 + (tid >> 2);
        int mrow = m0 + trow;
        if (mrow >= m_count) mrow = m_count - 1;
        long grow;
        if (GATHER)      grow = tok_of_row[m_base + mrow];
        else if (EXPERT) grow = m_base + mrow;
        else             grow = mrow;
        aptr[r] = A + (size_t)grow * K + swz(trow, tid & 3) * 8;
    }
    const unsigned short* bptr0[BR];
    const unsigned short* bptr1[BR];
#pragma unroll
    for (int r = 0; r < BR; ++r) {
        int trow = r * 64 + (tid >> 2);
        int gs = swz(trow, tid & 3) * 8;
        bptr0[r] = B0 + (size_t)(n0 + trow) * K + gs;
        if (DUAL) bptr1[r] = B1 + (size_t)(n0 + trow) * K + gs;
    }
    unsigned short* As_dst  = As  + tid * 8;
    unsigned short* Bs0_dst = Bs0 + tid * 8;
    unsigned short* Bs1_dst = DUAL ? (Bs1 + tid * 8) : nullptr;

    int wave = tid >> 6, lane = tid & 63;
    int wm0 = (wave >> 1) * 64;
    int wn0 = (wave & 1) * (BN_ / 2);
    int l15 = lane & 15, kg = lane >> 4;

    f32x4 acc0[4][NF] = {};
    f32x4 acc1[DUAL ? 4 : 1][DUAL ? NF : 1] = {};

    for (int k0 = 0; k0 < K; k0 += 32) {
#pragma unroll
        for (int r = 0; r < 2; ++r)
            gload_lds16(aptr[r] + k0, As_dst + r * 2048);
#pragma unroll
        for (int r = 0; r < BR; ++r) {
            gload_lds16(bptr0[r] + k0, Bs0_dst + r * 2048);
            if constexpr (DUAL) gload_lds16(bptr1[r] + k0, Bs1_dst + r * 2048);
        }
        __syncthreads();

        bf16x8 af[4];
#pragma unroll
        for (int mf = 0; mf < 4; ++mf) {
            int row = wm0 + mf * 16 + l15;
            af[mf] = *reinterpret_cast<const bf16x8*>(As + row * 32 + swz(row, kg) * 8);
        }
        bf16x8 bf0[NF], bf1[NF];
#pragma unroll
        for (int nf = 0; nf < NF; ++nf) {
            int row = wn0 + nf * 16 + l15;
            bf0[nf] = *reinterpret_cast<const bf16x8*>(Bs0 + row * 32 + swz(row, kg) * 8);
            if constexpr (DUAL)
                bf1[nf] = *reinterpret_cast<const bf16x8*>(Bs1 + row * 32 + swz(row, kg) * 8);
        }
#pragma unroll
        for (int mf = 0; mf < 4; ++mf)
#pragma unroll
            for (int nf = 0; nf < NF; ++nf) {
                acc0[mf][nf] = __builtin_amdgcn_mfma_f32_16x16x32_bf16(af[mf], bf0[nf], acc0[mf][nf], 0, 0, 0);
                if constexpr (DUAL)
                    acc1[mf][nf] = __builtin_amdgcn_mfma_f32_16x16x32_bf16(af[mf], bf1[nf], acc1[mf][nf], 0, 0, 0);
            }
        __syncthreads();
    }

#pragma unroll
    for (int mf = 0; mf < 4; ++mf) {
#pragma unroll
        for (int r4 = 0; r4 < 4; ++r4) {
            int mrow = m0 + wm0 + mf * 16 + kg * 4 + r4;
            if (mrow >= m_count) continue;
            size_t crow = (size_t)((EXPERT ? m_base : 0) + mrow) * ldc + ccol + n0 + wn0;
#pragma unroll
            for (int nf = 0; nf < NF; ++nf) {
                float v = acc0[mf][nf][r4];
                if constexpr (SILU) {
                    float g = v;
                    float a = acc1[mf][nf][r4];
                    v = (g / (1.f + expf(-g))) * a;
                }
                int col = nf * 16 + l15;
                if constexpr (OUT_BF16) ((unsigned short*)Cv)[crow + col] = f2bf(v);
                else                    ((float*)Cv)[crow + col] = v;
            }
        }
    }
}

// ================= dispatch 5: combine -> acat[:,0:256] (round-3 proven) =========
__global__ void combine_kernel(const float* __restrict__ ex,
                               const int* __restrict__ row_of_pair,
                               const float* __restrict__ topk_w,
                               unsigned short* __restrict__ acat)
{
    int i = blockIdx.x * 256 + threadIdx.x;
    int t = i >> 6;
    int l4 = (i & 63) * 4;
    int r0 = row_of_pair[2 * t], r1 = row_of_pair[2 * t + 1];
    float w0 = topk_w[2 * t], w1 = topk_w[2 * t + 1];
    float4 a = *(const float4*)(ex + (size_t)r0 * L_LAT + l4);
    float4 b = *(const float4*)(ex + (size_t)r1 * L_LAT + l4);
    ushort4 o = { f2bf(w0 * a.x + w1 * b.x), f2bf(w0 * a.y + w1 * b.y),
                  f2bf(w0 * a.z + w1 * b.z), f2bf(w0 * a.w + w1 * b.w) };
    *(ushort4*)(acat + (size_t)t * KCAT + l4) = o;
}

extern "C" void kernel_launch(void* const* d_in, const int* in_sizes, int n_in,
                              void* d_out, int out_size, void* d_ws, size_t ws_size,
                              hipStream_t stream)
{
    const float* x        = (const float*)d_in[0];
    const float* w_router = (const float*)d_in[1];
    const float* w_down   = (const float*)d_in[2];
    const float* w_up     = (const float*)d_in[3];
    const float* w1_e     = (const float*)d_in[4];
    const float* wg_e     = (const float*)d_in[5];
    const float* w2_e     = (const float*)d_in[6];
    const float* w1_s     = (const float*)d_in[7];
    const float* wg_s     = (const float*)d_in[8];
    const float* w2_s     = (const float*)d_in[9];
    float* out = (float*)d_out;

    char* ws = (char*)d_ws;
    size_t off = 0;
    auto alloc = [&](size_t bytes) -> void* {
        void* p = ws + off;
        off += (bytes + 255) & ~(size_t)255;
        return p;
    };
    unsigned short* x_bf    = (unsigned short*)alloc((size_t)T_TOK * D_MODEL * 2);   // 8 MB
    unsigned short* lat_bf  = (unsigned short*)alloc((size_t)T_TOK * L_LAT * 2);     // 2 MB
    unsigned short* acat    = (unsigned short*)alloc((size_t)T_TOK * KCAT * 2);      // 6 MB
    float*          ex      = (float*)alloc((size_t)TOT_EROWS * L_LAT * 4);          // 8 MB
    unsigned short* wdown_bf= (unsigned short*)alloc((size_t)L_LAT * D_MODEL * 2);
    unsigned short* wge_bf  = (unsigned short*)alloc((size_t)E_EXP * H_HID * L_LAT * 2);
    unsigned short* w1e_bf  = (unsigned short*)alloc((size_t)E_EXP * H_HID * L_LAT * 2);
    unsigned short* w2e_bf  = (unsigned short*)alloc((size_t)E_EXP * L_LAT * H_HID * 2);
    unsigned short* wgs_bf  = (unsigned short*)alloc((size_t)SH_HID * D_MODEL * 2);
    unsigned short* w1s_bf  = (unsigned short*)alloc((size_t)SH_HID * D_MODEL * 2);
    unsigned short* wcat_bf = (unsigned short*)alloc((size_t)D_MODEL * KCAT * 2);
    int*   topk_idx    = (int*)alloc(T_TOK * 2 * 4);
    float* topk_w      = (float*)alloc(T_TOK * 2 * 4);
    int*   tok_of_row  = (int*)alloc(T_TOK * 2 * 4);
    int*   row_of_pair = (int*)alloc(T_TOK * 2 * 4);
    int*   counts      = (int*)alloc(E_EXP * 4);
    int*   offsets     = (int*)alloc(E_EXP * 4);
    unsigned short* hbuf_bf = x_bf;   // alias: x_bf dead after k_main

    // 1) casts + wcat + router
    cast_router_kernel<<<10240, 256, 0, stream>>>(
        x, w_down, wg_e, w1_e, w2_e, wg_s, w1_s, w_up, w2_s, w_router,
        x_bf, wdown_bf, wge_bf, w1e_bf, w2e_bf, wgs_bf, w1s_bf, wcat_bf,
        topk_idx, topk_w);

    // 2) GEMM1 (lat) + GEMM2 (acat[:,256:768]) + bucket
    k_main<<<dim3(32, 13), 256, 0, stream>>>(
        x_bf, wdown_bf, wgs_bf, w1s_bf, lat_bf, acat,
        topk_idx, counts, offsets, tok_of_row, row_of_pair);

    // 3) expert up: hbuf = silu(lat@wg_e^T)*(lat@w1_e^T)  (gathered buckets)
    mfma_gemm<64, true, true, true, true, true>
        <<<dim3(TOT_EROWS / 128, H_HID / 64, E_EXP), 256, 0, stream>>>(
        lat_bf, wge_bf, w1e_bf, hbuf_bf, 0, H_HID, L_LAT, H_HID, 0,
        tok_of_row, offsets, counts, (long)H_HID * L_LAT);

    // 4) expert down: ex = hbuf @ w2_e^T  (fp32 out)
    mfma_gemm<64, false, false, true, false, false>
        <<<dim3(TOT_EROWS / 128, L_LAT / 64, E_EXP), 256, 0, stream>>>(
        hbuf_bf, w2e_bf, nullptr, ex, 0, L_LAT, H_HID, L_LAT, 0,
        nullptr, offsets, counts, (long)L_LAT * H_HID);

    // 5) combine -> acat[:,0:256]
    combine_kernel<<<T_TOK * L_LAT / 4 / 256, 256, 0, stream>>>(ex, row_of_pair, topk_w, acat);

    // 6) out = acat @ wcat^T  (4096 x 1024 x 768; fp32 out)
    mfma_gemm<128, false, false, false, false, false>
        <<<dim3(T_TOK / 128, D_MODEL / 128, 1), 256, 0, stream>>>(
        acat, wcat_bf, nullptr, out, T_TOK, D_MODEL, KCAT, D_MODEL, 0,
        nullptr, nullptr, nullptr, 0);
}

// Round 6
// 107.426 us; speedup vs baseline: 5.5582x; 1.2621x over previous
//
#include <hip/hip_runtime.h>
#include <hip/hip_bf16.h>
#include <math.h>

#define T_TOK 4096
#define D_MODEL 1024
#define L_LAT 256
#define H_HID 512
#define E_EXP 8
#define SH_HID 512
#define KCAT 768
#define TOT_EROWS (2 * T_TOK)

typedef __bf16 bf16x8 __attribute__((ext_vector_type(8)));
typedef float f32x4 __attribute__((ext_vector_type(4)));

__device__ __forceinline__ unsigned short f2bf(float f) {
    union { float f; unsigned int u; } c{f};
    unsigned int r = (c.u + 0x7fffu + ((c.u >> 16) & 1u)) >> 16;
    return (unsigned short)r;
}

__device__ __forceinline__ void gload_lds16(const unsigned short* g, unsigned short* l) {
    __builtin_amdgcn_global_load_lds(
        (const __attribute__((address_space(1))) void*)g,
        (__attribute__((address_space(3))) void*)l,
        16, 0, 0);
}

// 3-bit XOR slot swizzle for BK=64 rows (8 slots x 8 bf16 = 128 B row).
// Row stride = 32 banks exactly, so bank = slot group; XOR row&7 spreads
// 16 same-slot rows across all 8 slot groups (2-way max, free). Involution.
__device__ __forceinline__ int swz64(int row, int s) {
    return s ^ (row & 7);
}

// ================= dispatch 1: casts + wcat + router (jobs) =================
__global__ __launch_bounds__(256)
void cast_router_kernel(const float* __restrict__ x, const float* __restrict__ w_down,
                        const float* __restrict__ wg_e, const float* __restrict__ w1_e,
                        const float* __restrict__ w2_e, const float* __restrict__ wg_s,
                        const float* __restrict__ w1_s, const float* __restrict__ w_up,
                        const float* __restrict__ w2_s, const float* __restrict__ w_router,
                        unsigned short* __restrict__ xb, unsigned short* __restrict__ wdb,
                        unsigned short* __restrict__ wgeb, unsigned short* __restrict__ w1eb,
                        unsigned short* __restrict__ w2eb, unsigned short* __restrict__ wgsb,
                        unsigned short* __restrict__ w1sb, unsigned short* __restrict__ wcat,
                        int* __restrict__ topk_idx, float* __restrict__ topk_w)
{
    __shared__ float wlds[E_EXP * D_MODEL];   // 32 KB (router job only)
    int bid = blockIdx.x;
    int tid = threadIdx.x;

    if (bid < 8448) {
        int i = bid * 256 + tid;
        const float* src; unsigned short* dst; int base;
        if      (i < 1048576) { src = x;      dst = xb;   base = 0; }
        else if (i < 1114112) { src = w_down; dst = wdb;  base = 1048576; }
        else if (i < 1376256) { src = wg_e;   dst = wgeb; base = 1114112; }
        else if (i < 1638400) { src = w1_e;   dst = w1eb; base = 1376256; }
        else if (i < 1900544) { src = w2_e;   dst = w2eb; base = 1638400; }
        else if (i < 2031616) { src = wg_s;   dst = wgsb; base = 1900544; }
        else                  { src = w1_s;   dst = w1sb; base = 2031616; }
        int j = (i - base) * 4;
        float4 v = *(const float4*)(src + j);
        ushort4 o = { f2bf(v.x), f2bf(v.y), f2bf(v.z), f2bf(v.w) };
        *(ushort4*)(dst + j) = o;
        return;
    }
    if (bid < 9216) {
        int i = (bid - 8448) * 256 + tid;    // 196608 float4s
        int row = i / 192;
        int col = (i % 192) * 4;
        float4 v;
        if (col < 256) v = *(const float4*)(w_up + row * 256 + col);
        else           v = *(const float4*)(w2_s + row * 512 + (col - 256));
        ushort4 o = { f2bf(v.x), f2bf(v.y), f2bf(v.z), f2bf(v.w) };
        *(ushort4*)(wcat + row * KCAT + col) = o;
        return;
    }

    // ---- router job (exact fp32) ----
    int rb = bid - 9216;
    for (int i = tid * 4; i < E_EXP * D_MODEL; i += 256 * 4)
        *(float4*)(wlds + i) = *(const float4*)(w_router + i);
    __syncthreads();

    int wid = tid >> 6, lane = tid & 63;
    int t = rb * 4 + wid;
    const float* xr = x + (size_t)t * D_MODEL;
    float acc[E_EXP];
#pragma unroll
    for (int e = 0; e < E_EXP; ++e) acc[e] = 0.f;
#pragma unroll 4
    for (int i = 0; i < D_MODEL / 64; ++i) {
        int d = lane + i * 64;
        float xv = xr[d];
#pragma unroll
        for (int e = 0; e < E_EXP; ++e)
            acc[e] = fmaf(xv, wlds[e * D_MODEL + d], acc[e]);
    }
#pragma unroll
    for (int e = 0; e < E_EXP; ++e)
        for (int off = 32; off > 0; off >>= 1)
            acc[e] += __shfl_xor(acc[e], off, 64);
    if (lane == 0) {
        int i0 = 0; float v0 = acc[0];
#pragma unroll
        for (int e = 1; e < E_EXP; ++e) if (acc[e] > v0) { v0 = acc[e]; i0 = e; }
        int i1 = -1; float v1 = -INFINITY;
#pragma unroll
        for (int e = 0; e < E_EXP; ++e) if (e != i0 && acc[e] > v1) { v1 = acc[e]; i1 = e; }
        float e1 = expf(v1 - v0);
        topk_idx[2 * t] = i0; topk_idx[2 * t + 1] = i1;
        topk_w[2 * t] = 1.f / (1.f + e1);
        topk_w[2 * t + 1] = e1 / (1.f + e1);
    }
}

// ================= bucket body (deterministic, no atomics; 256 threads) =========
__device__ void bucket_body(const int* __restrict__ topk_idx,
                            int* __restrict__ counts, int* __restrict__ offsets,
                            int* __restrict__ tok_of_row, int* __restrict__ row_of_pair,
                            int* sb)
{
    int* s_wavecnt  = sb;        // [4][8]
    int* s_wavebase = sb + 32;   // [4][8]
    int* s_tot      = sb + 64;   // [8]
    int* s_off      = sb + 72;   // [8]
    int tid = threadIdx.x, wave = tid >> 6, lane = tid & 63;
    int base_i = tid * 32;       // 8192 items / 256 threads

    int cnt[E_EXP];
#pragma unroll
    for (int e = 0; e < E_EXP; ++e) cnt[e] = 0;
#pragma unroll
    for (int j = 0; j < 32; ++j) {
        int e = topk_idx[base_i + j];
#pragma unroll
        for (int q = 0; q < E_EXP; ++q) cnt[q] += (e == q) ? 1 : 0;
    }
    int excl[E_EXP];
#pragma unroll
    for (int e = 0; e < E_EXP; ++e) {
        int v = cnt[e];
#pragma unroll
        for (int off = 1; off < 64; off <<= 1) {
            int u = __shfl_up(v, off, 64);
            v += (lane >= off) ? u : 0;
        }
        excl[e] = v - cnt[e];
        if (lane == 63) s_wavecnt[wave * 8 + e] = v;
    }
    __syncthreads();
    if (tid < E_EXP) {
        int tot = 0;
        for (int w = 0; w < 4; ++w) tot += s_wavecnt[w * 8 + tid];
        s_tot[tid] = tot;
        counts[tid] = tot;
    }
    __syncthreads();
    if (tid == 0) {
        int off = 0;
        for (int e = 0; e < E_EXP; ++e) { s_off[e] = off; offsets[e] = off; off += s_tot[e]; }
    }
    __syncthreads();
    if (tid < E_EXP) {
        int run = s_off[tid];
        for (int w = 0; w < 4; ++w) { s_wavebase[w * 8 + tid] = run; run += s_wavecnt[w * 8 + tid]; }
    }
    __syncthreads();
    int tb[E_EXP];
#pragma unroll
    for (int e = 0; e < E_EXP; ++e) tb[e] = s_wavebase[wave * 8 + e] + excl[e];
#pragma unroll
    for (int j = 0; j < 32; ++j) {
        int item = base_i + j;
        int e = topk_idx[item];
        int p = 0;
#pragma unroll
        for (int q = 0; q < E_EXP; ++q) if (e == q) { p = tb[q]; tb[q] = p + 1; }
        tok_of_row[p] = item >> 1;
        row_of_pair[item] = p;
    }
}

// ================= dispatch 2: GEMM1 + GEMM2 + bucket (jobs), BK=64 ============
// y in [0,4): GEMM1 lat = x@w_down^T (N=256). y in [4,12): GEMM2 acat[:,256:768].
// y == 12, x == 0: bucket.
__global__ __launch_bounds__(256)
void k_main(const unsigned short* __restrict__ x_bf,
            const unsigned short* __restrict__ wdown_bf,
            const unsigned short* __restrict__ wgs_bf,
            const unsigned short* __restrict__ w1s_bf,
            unsigned short* __restrict__ lat_bf,
            unsigned short* __restrict__ acat,
            const int* __restrict__ topk_idx,
            int* __restrict__ counts, int* __restrict__ offsets,
            int* __restrict__ tok_of_row, int* __restrict__ row_of_pair)
{
    __shared__ __align__(16) unsigned short As[128 * 64];   // 16 KB
    __shared__ __align__(16) unsigned short Bs0[64 * 64];   // 8 KB
    __shared__ __align__(16) unsigned short Bs1[64 * 64];   // 8 KB

    int y = blockIdx.y;
    if (y == 12) {
        if (blockIdx.x == 0)
            bucket_body(topk_idx, counts, offsets, tok_of_row, row_of_pair, (int*)As);
        return;
    }
    bool dual = (y >= 4);
    int n0 = dual ? (y - 4) * 64 : y * 64;
    const unsigned short* B0 = dual ? wgs_bf : wdown_bf;
    unsigned short* C = dual ? (acat + L_LAT) : lat_bf;   // GEMM2 -> acat cols 256:768
    int ldc = dual ? KCAT : L_LAT;

    int m0 = blockIdx.x * 128;
    int tid = threadIdx.x;
    int r8 = tid >> 3, slot = tid & 7;

    const unsigned short* aptr[4];
#pragma unroll
    for (int r = 0; r < 4; ++r) {
        int rl = r * 32 + r8;
        aptr[r] = x_bf + (size_t)(m0 + rl) * D_MODEL + swz64(rl, slot) * 8;
    }
    const unsigned short* bptr0[2];
    const unsigned short* bptr1[2];
#pragma unroll
    for (int r = 0; r < 2; ++r) {
        int rl = r * 32 + r8;
        int gs = swz64(rl, slot) * 8;
        bptr0[r] = B0 + (size_t)(n0 + rl) * D_MODEL + gs;
        bptr1[r] = w1s_bf + (size_t)(n0 + rl) * D_MODEL + gs;
    }
    unsigned short* As_dst  = As  + tid * 8;
    unsigned short* Bs0_dst = Bs0 + tid * 8;
    unsigned short* Bs1_dst = Bs1 + tid * 8;

    int wave = tid >> 6, lane = tid & 63;
    int wm0 = (wave >> 1) * 64, wn0 = (wave & 1) * 32;
    int l15 = lane & 15, kg = lane >> 4;

    f32x4 acc0[4][2] = {};
    f32x4 acc1[4][2] = {};

    for (int k0 = 0; k0 < D_MODEL; k0 += 64) {
#pragma unroll
        for (int r = 0; r < 4; ++r)
            gload_lds16(aptr[r] + k0, As_dst + r * 2048);
#pragma unroll
        for (int r = 0; r < 2; ++r) {
            gload_lds16(bptr0[r] + k0, Bs0_dst + r * 2048);
            if (dual) gload_lds16(bptr1[r] + k0, Bs1_dst + r * 2048);
        }
        __syncthreads();

        bf16x8 af[2][4];
#pragma unroll
        for (int kh = 0; kh < 2; ++kh)
#pragma unroll
            for (int mf = 0; mf < 4; ++mf) {
                int row = wm0 + mf * 16 + l15;
                af[kh][mf] = *reinterpret_cast<const bf16x8*>(As + row * 64 + swz64(row, kh * 4 + kg) * 8);
            }
        bf16x8 bf0[2][2], bf1[2][2];
#pragma unroll
        for (int kh = 0; kh < 2; ++kh)
#pragma unroll
            for (int nf = 0; nf < 2; ++nf) {
                int row = wn0 + nf * 16 + l15;
                bf0[kh][nf] = *reinterpret_cast<const bf16x8*>(Bs0 + row * 64 + swz64(row, kh * 4 + kg) * 8);
            }
        if (dual) {
#pragma unroll
            for (int kh = 0; kh < 2; ++kh)
#pragma unroll
                for (int nf = 0; nf < 2; ++nf) {
                    int row = wn0 + nf * 16 + l15;
                    bf1[kh][nf] = *reinterpret_cast<const bf16x8*>(Bs1 + row * 64 + swz64(row, kh * 4 + kg) * 8);
                }
        }
#pragma unroll
        for (int kh = 0; kh < 2; ++kh)
#pragma unroll
            for (int mf = 0; mf < 4; ++mf)
#pragma unroll
                for (int nf = 0; nf < 2; ++nf)
                    acc0[mf][nf] = __builtin_amdgcn_mfma_f32_16x16x32_bf16(af[kh][mf], bf0[kh][nf], acc0[mf][nf], 0, 0, 0);
        if (dual) {
#pragma unroll
            for (int kh = 0; kh < 2; ++kh)
#pragma unroll
                for (int mf = 0; mf < 4; ++mf)
#pragma unroll
                    for (int nf = 0; nf < 2; ++nf)
                        acc1[mf][nf] = __builtin_amdgcn_mfma_f32_16x16x32_bf16(af[kh][mf], bf1[kh][nf], acc1[mf][nf], 0, 0, 0);
        }
        __syncthreads();
    }

#pragma unroll
    for (int mf = 0; mf < 4; ++mf)
#pragma unroll
        for (int r4 = 0; r4 < 4; ++r4) {
            int mrow = m0 + wm0 + mf * 16 + kg * 4 + r4;
            size_t crow = (size_t)mrow * ldc + n0 + wn0;
#pragma unroll
            for (int nf = 0; nf < 2; ++nf) {
                float v = acc0[mf][nf][r4];
                if (dual) {
                    float g = v, a = acc1[mf][nf][r4];
                    v = (g / (1.f + expf(-g))) * a;
                }
                C[crow + nf * 16 + l15] = f2bf(v);
            }
        }
}

// ================= dispatches 3/4/6: MFMA NT GEMM template, BK=64 ==============
template<bool DUAL, bool SILU, bool EXPERT, bool GATHER, bool OUT_BF16>
__global__ __launch_bounds__(256)
void mfma_gemm(const unsigned short* __restrict__ A,
               const unsigned short* __restrict__ B0g,
               const unsigned short* __restrict__ B1g,
               void* __restrict__ Cv,
               int M, int N, int K, int ldc, int ccol,
               const int* __restrict__ tok_of_row,
               const int* __restrict__ offsets,
               const int* __restrict__ counts,
               long strideB)
{
    __shared__ __align__(16) unsigned short As[128 * 64];   // 16 KB
    __shared__ __align__(16) unsigned short Bs0[64 * 64];   // 8 KB
    __shared__ __align__(16) unsigned short Bs1[DUAL ? 64 * 64 : 8];

    int e = EXPERT ? blockIdx.z : 0;
    int m_base = 0, m_count = M;
    if (EXPERT) { m_base = offsets[e]; m_count = counts[e]; }
    int m0 = blockIdx.x * 128;
    if (m0 >= m_count) return;
    int n0 = blockIdx.y * 64;

    const unsigned short* B0 = B0g + (EXPERT ? (size_t)e * strideB : 0);
    const unsigned short* B1 = DUAL ? (B1g + (EXPERT ? (size_t)e * strideB : 0)) : nullptr;

    int tid = threadIdx.x;
    int r8 = tid >> 3, slot = tid & 7;

    const unsigned short* aptr[4];
#pragma unroll
    for (int r = 0; r < 4; ++r) {
        int rl = r * 32 + r8;
        int mrow = m0 + rl;
        if (mrow >= m_count) mrow = m_count - 1;      // clamp (epilogue masks)
        long grow;
        if (GATHER)      grow = tok_of_row[m_base + mrow];
        else if (EXPERT) grow = m_base + mrow;
        else             grow = mrow;
        aptr[r] = A + (size_t)grow * K + swz64(rl, slot) * 8;
    }
    const unsigned short* bptr0[2];
    const unsigned short* bptr1[2];
#pragma unroll
    for (int r = 0; r < 2; ++r) {
        int rl = r * 32 + r8;
        int gs = swz64(rl, slot) * 8;
        bptr0[r] = B0 + (size_t)(n0 + rl) * K + gs;
        if (DUAL) bptr1[r] = B1 + (size_t)(n0 + rl) * K + gs;
    }
    unsigned short* As_dst  = As  + tid * 8;
    unsigned short* Bs0_dst = Bs0 + tid * 8;
    unsigned short* Bs1_dst = DUAL ? (Bs1 + tid * 8) : nullptr;

    int wave = tid >> 6, lane = tid & 63;
    int wm0 = (wave >> 1) * 64, wn0 = (wave & 1) * 32;
    int l15 = lane & 15, kg = lane >> 4;

    f32x4 acc0[4][2] = {};
    f32x4 acc1[DUAL ? 4 : 1][DUAL ? 2 : 1] = {};

    for (int k0 = 0; k0 < K; k0 += 64) {
#pragma unroll
        for (int r = 0; r < 4; ++r)
            gload_lds16(aptr[r] + k0, As_dst + r * 2048);
#pragma unroll
        for (int r = 0; r < 2; ++r) {
            gload_lds16(bptr0[r] + k0, Bs0_dst + r * 2048);
            if constexpr (DUAL) gload_lds16(bptr1[r] + k0, Bs1_dst + r * 2048);
        }
        __syncthreads();

        bf16x8 af[2][4];
#pragma unroll
        for (int kh = 0; kh < 2; ++kh)
#pragma unroll
            for (int mf = 0; mf < 4; ++mf) {
                int row = wm0 + mf * 16 + l15;
                af[kh][mf] = *reinterpret_cast<const bf16x8*>(As + row * 64 + swz64(row, kh * 4 + kg) * 8);
            }
        bf16x8 bf0[2][2], bf1[2][2];
#pragma unroll
        for (int kh = 0; kh < 2; ++kh)
#pragma unroll
            for (int nf = 0; nf < 2; ++nf) {
                int row = wn0 + nf * 16 + l15;
                bf0[kh][nf] = *reinterpret_cast<const bf16x8*>(Bs0 + row * 64 + swz64(row, kh * 4 + kg) * 8);
                if constexpr (DUAL)
                    bf1[kh][nf] = *reinterpret_cast<const bf16x8*>(Bs1 + row * 64 + swz64(row, kh * 4 + kg) * 8);
            }
#pragma unroll
        for (int kh = 0; kh < 2; ++kh)
#pragma unroll
            for (int mf = 0; mf < 4; ++mf)
#pragma unroll
                for (int nf = 0; nf < 2; ++nf) {
                    acc0[mf][nf] = __builtin_amdgcn_mfma_f32_16x16x32_bf16(af[kh][mf], bf0[kh][nf], acc0[mf][nf], 0, 0, 0);
                    if constexpr (DUAL)
                        acc1[mf][nf] = __builtin_amdgcn_mfma_f32_16x16x32_bf16(af[kh][mf], bf1[kh][nf], acc1[mf][nf], 0, 0, 0);
                }
        __syncthreads();
    }

#pragma unroll
    for (int mf = 0; mf < 4; ++mf) {
#pragma unroll
        for (int r4 = 0; r4 < 4; ++r4) {
            int mrow = m0 + wm0 + mf * 16 + kg * 4 + r4;
            if (mrow >= m_count) continue;
            size_t crow = (size_t)((EXPERT ? m_base : 0) + mrow) * ldc + ccol + n0 + wn0;
#pragma unroll
            for (int nf = 0; nf < 2; ++nf) {
                float v = acc0[mf][nf][r4];
                if constexpr (SILU) {
                    float g = v;
                    float a = acc1[mf][nf][r4];
                    v = (g / (1.f + expf(-g))) * a;
                }
                int col = nf * 16 + l15;
                if constexpr (OUT_BF16) ((unsigned short*)Cv)[crow + col] = f2bf(v);
                else                    ((float*)Cv)[crow + col] = v;
            }
        }
    }
}

// ================= dispatch 5: combine -> acat[:,0:256] =========
__global__ void combine_kernel(const float* __restrict__ ex,
                               const int* __restrict__ row_of_pair,
                               const float* __restrict__ topk_w,
                               unsigned short* __restrict__ acat)
{
    int i = blockIdx.x * 256 + threadIdx.x;
    int t = i >> 6;
    int l4 = (i & 63) * 4;
    int r0 = row_of_pair[2 * t], r1 = row_of_pair[2 * t + 1];
    float w0 = topk_w[2 * t], w1 = topk_w[2 * t + 1];
    float4 a = *(const float4*)(ex + (size_t)r0 * L_LAT + l4);
    float4 b = *(const float4*)(ex + (size_t)r1 * L_LAT + l4);
    ushort4 o = { f2bf(w0 * a.x + w1 * b.x), f2bf(w0 * a.y + w1 * b.y),
                  f2bf(w0 * a.z + w1 * b.z), f2bf(w0 * a.w + w1 * b.w) };
    *(ushort4*)(acat + (size_t)t * KCAT + l4) = o;
}

extern "C" void kernel_launch(void* const* d_in, const int* in_sizes, int n_in,
                              void* d_out, int out_size, void* d_ws, size_t ws_size,
                              hipStream_t stream)
{
    const float* x        = (const float*)d_in[0];
    const float* w_router = (const float*)d_in[1];
    const float* w_down   = (const float*)d_in[2];
    const float* w_up     = (const float*)d_in[3];
    const float* w1_e     = (const float*)d_in[4];
    const float* wg_e     = (const float*)d_in[5];
    const float* w2_e     = (const float*)d_in[6];
    const float* w1_s     = (const float*)d_in[7];
    const float* wg_s     = (const float*)d_in[8];
    const float* w2_s     = (const float*)d_in[9];
    float* out = (float*)d_out;

    char* ws = (char*)d_ws;
    size_t off = 0;
    auto alloc = [&](size_t bytes) -> void* {
        void* p = ws + off;
        off += (bytes + 255) & ~(size_t)255;
        return p;
    };
    unsigned short* x_bf    = (unsigned short*)alloc((size_t)T_TOK * D_MODEL * 2);   // 8 MB
    unsigned short* lat_bf  = (unsigned short*)alloc((size_t)T_TOK * L_LAT * 2);     // 2 MB
    unsigned short* acat    = (unsigned short*)alloc((size_t)T_TOK * KCAT * 2);      // 6 MB
    float*          ex      = (float*)alloc((size_t)TOT_EROWS * L_LAT * 4);          // 8 MB
    unsigned short* wdown_bf= (unsigned short*)alloc((size_t)L_LAT * D_MODEL * 2);
    unsigned short* wge_bf  = (unsigned short*)alloc((size_t)E_EXP * H_HID * L_LAT * 2);
    unsigned short* w1e_bf  = (unsigned short*)alloc((size_t)E_EXP * H_HID * L_LAT * 2);
    unsigned short* w2e_bf  = (unsigned short*)alloc((size_t)E_EXP * L_LAT * H_HID * 2);
    unsigned short* wgs_bf  = (unsigned short*)alloc((size_t)SH_HID * D_MODEL * 2);
    unsigned short* w1s_bf  = (unsigned short*)alloc((size_t)SH_HID * D_MODEL * 2);
    unsigned short* wcat_bf = (unsigned short*)alloc((size_t)D_MODEL * KCAT * 2);
    int*   topk_idx    = (int*)alloc(T_TOK * 2 * 4);
    float* topk_w      = (float*)alloc(T_TOK * 2 * 4);
    int*   tok_of_row  = (int*)alloc(T_TOK * 2 * 4);
    int*   row_of_pair = (int*)alloc(T_TOK * 2 * 4);
    int*   counts      = (int*)alloc(E_EXP * 4);
    int*   offsets     = (int*)alloc(E_EXP * 4);
    unsigned short* hbuf_bf = x_bf;   // alias: x_bf dead after k_main

    // 1) casts + wcat + router
    cast_router_kernel<<<10240, 256, 0, stream>>>(
        x, w_down, wg_e, w1_e, w2_e, wg_s, w1_s, w_up, w2_s, w_router,
        x_bf, wdown_bf, wge_bf, w1e_bf, w2e_bf, wgs_bf, w1s_bf, wcat_bf,
        topk_idx, topk_w);

    // 2) GEMM1 (lat) + GEMM2 (acat[:,256:768]) + bucket
    k_main<<<dim3(32, 13), 256, 0, stream>>>(
        x_bf, wdown_bf, wgs_bf, w1s_bf, lat_bf, acat,
        topk_idx, counts, offsets, tok_of_row, row_of_pair);

    // 3) expert up: hbuf = silu(lat@wg_e^T)*(lat@w1_e^T)  (gathered buckets)
    mfma_gemm<true, true, true, true, true>
        <<<dim3(TOT_EROWS / 128, H_HID / 64, E_EXP), 256, 0, stream>>>(
        lat_bf, wge_bf, w1e_bf, hbuf_bf, 0, H_HID, L_LAT, H_HID, 0,
        tok_of_row, offsets, counts, (long)H_HID * L_LAT);

    // 4) expert down: ex = hbuf @ w2_e^T  (fp32 out)
    mfma_gemm<false, false, true, false, false>
        <<<dim3(TOT_EROWS / 128, L_LAT / 64, E_EXP), 256, 0, stream>>>(
        hbuf_bf, w2e_bf, nullptr, ex, 0, L_LAT, H_HID, L_LAT, 0,
        nullptr, offsets, counts, (long)L_LAT * H_HID);

    // 5) combine -> acat[:,0:256]
    combine_kernel<<<T_TOK * L_LAT / 4 / 256, 256, 0, stream>>>(ex, row_of_pair, topk_w, acat);

    // 6) out = acat @ wcat^T  (4096 x 1024 x 768; fp32 out; 512 blocks = 2/CU)
    mfma_gemm<false, false, false, false, false>
        <<<dim3(T_TOK / 128, D_MODEL / 64, 1), 256, 0, stream>>>(
        acat, wcat_bf, nullptr, out, T_TOK, D_MODEL, KCAT, D_MODEL, 0,
        nullptr, nullptr, nullptr, 0);
}